// Round 1
// baseline (1060.560 us; speedup 1.0000x reference)
//
#include <hip/hip_runtime.h>
#include <hip/hip_bf16.h>
#include <math.h>

#define NN 50000
#define EE 800000
#define ET 850000   // EE + NN self loops
#define F1 256      // NHEAD*HID
#define NHEAD 8
#define HID 32
#define NCLASS 40
#define NEG 0.2f

__device__ __forceinline__ int clampN(int v) {
    return v < 0 ? 0 : (v >= NN ? NN - 1 : v);
}

// ---------------- CSR construction ----------------
__global__ __launch_bounds__(256) void hist_kernel(const int* __restrict__ ei, int* __restrict__ deg) {
    int t = blockIdx.x * 256 + threadIdx.x;
    if (t >= ET) return;
    int d = (t < EE) ? ei[EE + t] : (t - EE);
    d = clampN(d);
    atomicAdd(&deg[d], 1);
}

__global__ __launch_bounds__(256) void scan1_kernel(const int* __restrict__ deg, int* __restrict__ off, int* __restrict__ bsum) {
    __shared__ int lds[256];
    int b = blockIdx.x, tid = threadIdx.x;
    int base = b * 1024 + tid * 4;
    int v0 = (base + 0 < NN) ? deg[base + 0] : 0;
    int v1 = (base + 1 < NN) ? deg[base + 1] : 0;
    int v2 = (base + 2 < NN) ? deg[base + 2] : 0;
    int v3 = (base + 3 < NN) ? deg[base + 3] : 0;
    int s1 = v0 + v1, s2 = s1 + v2, s3 = s2 + v3;
    lds[tid] = s3;
    __syncthreads();
    for (int o = 1; o < 256; o <<= 1) {
        int t = (tid >= o) ? lds[tid - o] : 0;
        __syncthreads();
        if (tid >= o) lds[tid] += t;
        __syncthreads();
    }
    int excl = tid ? lds[tid - 1] : 0;
    if (base + 0 < NN) off[base + 1] = excl + v0;
    if (base + 1 < NN) off[base + 2] = excl + s1;
    if (base + 2 < NN) off[base + 3] = excl + s2;
    if (base + 3 < NN) off[base + 4] = excl + s3;
    if (tid == 255) bsum[b] = lds[255];
}

__global__ __launch_bounds__(256) void scan2_kernel(int* __restrict__ bsum, int nb) {
    __shared__ int lds[256];
    int tid = threadIdx.x;
    lds[tid] = (tid < nb) ? bsum[tid] : 0;
    __syncthreads();
    for (int o = 1; o < 256; o <<= 1) {
        int t = (tid >= o) ? lds[tid - o] : 0;
        __syncthreads();
        if (tid >= o) lds[tid] += t;
        __syncthreads();
    }
    if (tid < nb) bsum[tid] = lds[tid];
}

__global__ __launch_bounds__(256) void scan3_kernel(int* __restrict__ off, const int* __restrict__ bsum) {
    int b = blockIdx.x, tid = threadIdx.x;
    if (b == 0 && tid == 0) off[0] = 0;
    if (b == 0) return;
    int add = bsum[b - 1];
    int base = b * 1024 + tid * 4;
    #pragma unroll
    for (int i = 0; i < 4; ++i) {
        if (base + i < NN) off[base + i + 1] += add;
    }
}

__global__ __launch_bounds__(256) void scatter_kernel(const int* __restrict__ ei, const int* __restrict__ off,
                                                      int* __restrict__ cursor, int* __restrict__ eids) {
    int t = blockIdx.x * 256 + threadIdx.x;
    if (t >= ET) return;
    int d = (t < EE) ? ei[EE + t] : (t - EE);
    d = clampN(d);
    int p = off[d] + atomicAdd(&cursor[d], 1);
    eids[p] = t;
}

// ---------------- GEMM1: h1 = x @ W1  [50000,256]x[256,256] fp32 ----------------
__global__ __launch_bounds__(256) void gemm1_kernel(const float* __restrict__ A, const float* __restrict__ B,
                                                    float* __restrict__ C) {
    __shared__ __align__(16) float As[16][68];
    __shared__ __align__(16) float Bs[16][68];
    int tid = threadIdx.x;
    int bx = blockIdx.x, by = blockIdx.y;
    int tx = tid & 15, ty = tid >> 4;
    int row0 = by * 64;
    float acc[4][4] = {};
    int lm = tid >> 2;          // A tile row 0..63
    int lk = (tid & 3) * 4;     // A k offset
    int bk = tid >> 4;          // B tile k row 0..15
    int bn = (tid & 15) * 4;    // B tile col offset
    for (int k0 = 0; k0 < 256; k0 += 16) {
        int ar = row0 + lm;
        float4 av = make_float4(0.f, 0.f, 0.f, 0.f);
        if (ar < NN) av = *(const float4*)(A + (size_t)ar * 256 + k0 + lk);
        As[lk + 0][lm] = av.x;
        As[lk + 1][lm] = av.y;
        As[lk + 2][lm] = av.z;
        As[lk + 3][lm] = av.w;
        float4 bv = *(const float4*)(B + (size_t)(k0 + bk) * 256 + bx * 64 + bn);
        *(float4*)(&Bs[bk][bn]) = bv;
        __syncthreads();
        #pragma unroll
        for (int k = 0; k < 16; ++k) {
            float4 a4 = *(const float4*)(&As[k][ty * 4]);
            float4 b4 = *(const float4*)(&Bs[k][tx * 4]);
            float a[4] = {a4.x, a4.y, a4.z, a4.w};
            float b[4] = {b4.x, b4.y, b4.z, b4.w};
            #pragma unroll
            for (int i = 0; i < 4; ++i)
                #pragma unroll
                for (int j = 0; j < 4; ++j)
                    acc[i][j] += a[i] * b[j];
        }
        __syncthreads();
    }
    #pragma unroll
    for (int i = 0; i < 4; ++i) {
        int r = row0 + ty * 4 + i;
        if (r < NN) {
            float4 o = make_float4(acc[i][0], acc[i][1], acc[i][2], acc[i][3]);
            *(float4*)(C + (size_t)r * 256 + bx * 64 + tx * 4) = o;
        }
    }
}

// ---------------- attention logits layer 1 ----------------
__global__ __launch_bounds__(256) void alpha1_kernel(const float* __restrict__ h1, const float* __restrict__ as,
                                                     const float* __restrict__ ad, float* __restrict__ o_s,
                                                     float* __restrict__ o_d) {
    int n = blockIdx.x;
    int t = threadIdx.x;
    float v = h1[(size_t)n * 256 + t];
    float ps = v * as[t];
    float pd = v * ad[t];
    for (int o = 16; o; o >>= 1) {
        ps += __shfl_down(ps, o, 32);
        pd += __shfl_down(pd, o, 32);
    }
    if ((t & 31) == 0) {
        o_s[n * 8 + (t >> 5)] = ps;
        o_d[n * 8 + (t >> 5)] = pd;
    }
}

// ---------------- layer-1 aggregation: wave per dst node ----------------
__global__ __launch_bounds__(256) void agg1_kernel(const float* __restrict__ h1, const float* __restrict__ asrc,
                                                   const float* __restrict__ adst, const int* __restrict__ ei,
                                                   const int* __restrict__ off, const int* __restrict__ eids,
                                                   const float* __restrict__ b1, float* __restrict__ hout) {
    int wid = blockIdx.x * 4 + (threadIdx.x >> 6);
    if (wid >= NN) return;
    int lane = threadIdx.x & 63;
    int hh = lane >> 3;       // head for attention
    int c0 = lane * 4;        // channels owned
    int d = wid;
    float adh = adst[d * 8 + hh];
    int e0 = off[d], e1 = off[d + 1];
    float m = -INFINITY, s = 0.f;
    for (int i = e0; i < e1; ++i) {
        int t = eids[i];
        int sn = (t < EE) ? ei[t] : (t - EE);
        sn = clampN(sn);
        float e = asrc[sn * 8 + hh] + adh;
        e = (e >= 0.f) ? e : NEG * e;
        float mn = fmaxf(m, e);
        s = s * __expf(m - mn) + __expf(e - mn);
        m = mn;
    }
    float inv = 1.f / (s + 1e-16f);
    float4 acc = make_float4(0.f, 0.f, 0.f, 0.f);
    for (int i = e0; i < e1; ++i) {
        int t = eids[i];
        int sn = (t < EE) ? ei[t] : (t - EE);
        sn = clampN(sn);
        float e = asrc[sn * 8 + hh] + adh;
        e = (e >= 0.f) ? e : NEG * e;
        float w = __expf(e - m) * inv;
        float4 hv = *(const float4*)(h1 + (size_t)sn * 256 + c0);
        acc.x += w * hv.x;
        acc.y += w * hv.y;
        acc.z += w * hv.z;
        acc.w += w * hv.w;
    }
    float4 b = *(const float4*)(b1 + c0);
    float4 o;
    float vx = acc.x + b.x, vy = acc.y + b.y, vz = acc.z + b.z, vw = acc.w + b.w;
    o.x = (vx > 0.f) ? vx : expm1f(vx);
    o.y = (vy > 0.f) ? vy : expm1f(vy);
    o.z = (vz > 0.f) ? vz : expm1f(vz);
    o.w = (vw > 0.f) ? vw : expm1f(vw);
    *(float4*)(hout + (size_t)d * 256 + c0) = o;
}

// ---------------- GEMM2 + attention logits layer 2 ----------------
__global__ __launch_bounds__(256) void gemm2_kernel(const float* __restrict__ h, const float* __restrict__ W2,
                                                    const float* __restrict__ at_s, const float* __restrict__ at_d,
                                                    float* __restrict__ h2, float* __restrict__ as2,
                                                    float* __restrict__ ad2) {
    __shared__ __align__(16) float w2s[256 * 40];
    for (int i = threadIdx.x; i < 256 * 40; i += 256) w2s[i] = W2[i];
    __syncthreads();
    int lane = threadIdx.x & 63;
    int c = lane;
    int stride = gridDim.x * 4;
    for (int wid = blockIdx.x * 4 + (threadIdx.x >> 6); wid < NN; wid += stride) {
        const float* hr = h + (size_t)wid * 256;
        float acc = 0.f;
        #pragma unroll 4
        for (int k = 0; k < 256; k += 4) {
            float4 hv = *(const float4*)(hr + k);
            if (c < NCLASS) {
                acc += hv.x * w2s[(k + 0) * 40 + c];
                acc += hv.y * w2s[(k + 1) * 40 + c];
                acc += hv.z * w2s[(k + 2) * 40 + c];
                acc += hv.w * w2s[(k + 3) * 40 + c];
            }
        }
        float v = (c < NCLASS) ? acc : 0.f;
        if (c < NCLASS) h2[(size_t)wid * 40 + c] = v;
        float ps = (c < NCLASS) ? v * at_s[c] : 0.f;
        float pd = (c < NCLASS) ? v * at_d[c] : 0.f;
        for (int o = 32; o; o >>= 1) {
            ps += __shfl_xor(ps, o);
            pd += __shfl_xor(pd, o);
        }
        if (lane == 0) {
            as2[wid] = ps;
            ad2[wid] = pd;
        }
    }
}

// ---------------- layer-2 aggregation + bias + log_softmax ----------------
__global__ __launch_bounds__(256) void agg2_kernel(const float* __restrict__ h2, const float* __restrict__ asrc,
                                                   const float* __restrict__ adst, const int* __restrict__ ei,
                                                   const int* __restrict__ off, const int* __restrict__ eids,
                                                   const float* __restrict__ b2, float* __restrict__ outF,
                                                   float* __restrict__ outL) {
    int wid = blockIdx.x * 4 + (threadIdx.x >> 6);
    if (wid >= NN) return;
    int lane = threadIdx.x & 63;
    int c = lane;
    int d = wid;
    float adh = adst[d];
    int e0 = off[d], e1 = off[d + 1];
    float m = -INFINITY, s = 0.f;
    for (int i = e0; i < e1; ++i) {
        int t = eids[i];
        int sn = (t < EE) ? ei[t] : (t - EE);
        sn = clampN(sn);
        float e = asrc[sn] + adh;
        e = (e >= 0.f) ? e : NEG * e;
        float mn = fmaxf(m, e);
        s = s * __expf(m - mn) + __expf(e - mn);
        m = mn;
    }
    float inv = 1.f / (s + 1e-16f);
    float acc = 0.f;
    for (int i = e0; i < e1; ++i) {
        int t = eids[i];
        int sn = (t < EE) ? ei[t] : (t - EE);
        sn = clampN(sn);
        float e = asrc[sn] + adh;
        e = (e >= 0.f) ? e : NEG * e;
        float w = __expf(e - m) * inv;
        if (c < NCLASS) acc += w * h2[(size_t)sn * 40 + c];
    }
    float fin = (c < NCLASS) ? (acc + b2[c]) : -INFINITY;
    if (c < NCLASS) outF[(size_t)d * 40 + c] = fin;
    // log_softmax across 40 classes
    float mx = fin;
    for (int o = 32; o; o >>= 1) mx = fmaxf(mx, __shfl_xor(mx, o));
    float ex = (c < NCLASS) ? __expf(fin - mx) : 0.f;
    float sm = ex;
    for (int o = 32; o; o >>= 1) sm += __shfl_xor(sm, o);
    if (c < NCLASS) outL[(size_t)d * 40 + c] = fin - mx - __logf(sm);
}

extern "C" void kernel_launch(void* const* d_in, const int* in_sizes, int n_in,
                              void* d_out, int out_size, void* d_ws, size_t ws_size,
                              hipStream_t stream) {
    const float* x   = (const float*)d_in[0];
    const int*   ei  = (const int*)d_in[1];
    const float* W1  = (const float*)d_in[3];
    const float* as1 = (const float*)d_in[4];
    const float* ad1 = (const float*)d_in[5];
    const float* b1  = (const float*)d_in[6];
    const float* W2  = (const float*)d_in[7];
    const float* as2c = (const float*)d_in[8];
    const float* ad2c = (const float*)d_in[9];
    const float* b2  = (const float*)d_in[10];

    float* outF = (float*)d_out;
    float* outL = outF + (size_t)NN * NCLASS;

    char* w = (char*)d_ws;
    auto alloc = [&](size_t bytes) {
        void* p = (void*)w;
        w += (bytes + 255) & ~(size_t)255;
        return p;
    };
    float* h1    = (float*)alloc((size_t)NN * 256 * 4);
    float* hbuf  = (float*)alloc((size_t)NN * 256 * 4);
    float* h2    = (float*)alloc((size_t)NN * 40 * 4);
    float* asrc1 = (float*)alloc((size_t)NN * 8 * 4);
    float* adst1 = (float*)alloc((size_t)NN * 8 * 4);
    float* asrc2 = (float*)alloc((size_t)NN * 4);
    float* adst2 = (float*)alloc((size_t)NN * 4);
    int* deg    = (int*)alloc((size_t)NN * 4);
    int* off    = (int*)alloc((size_t)(NN + 1) * 4);
    int* cursor = (int*)alloc((size_t)NN * 4);
    int* eids   = (int*)alloc((size_t)ET * 4);
    int* bsum   = (int*)alloc(64 * 4);

    const int NB_SCAN = (NN + 1023) / 1024;  // 49

    hipMemsetAsync(deg, 0, (size_t)NN * 4, stream);
    hipMemsetAsync(cursor, 0, (size_t)NN * 4, stream);

    hist_kernel<<<(ET + 255) / 256, 256, 0, stream>>>(ei, deg);
    scan1_kernel<<<NB_SCAN, 256, 0, stream>>>(deg, off, bsum);
    scan2_kernel<<<1, 256, 0, stream>>>(bsum, NB_SCAN);
    scan3_kernel<<<NB_SCAN, 256, 0, stream>>>(off, bsum);
    scatter_kernel<<<(ET + 255) / 256, 256, 0, stream>>>(ei, off, cursor, eids);

    gemm1_kernel<<<dim3(4, (NN + 63) / 64), 256, 0, stream>>>(x, W1, h1);
    alpha1_kernel<<<NN, 256, 0, stream>>>(h1, as1, ad1, asrc1, adst1);
    agg1_kernel<<<(NN + 3) / 4, 256, 0, stream>>>(h1, asrc1, adst1, ei, off, eids, b1, hbuf);
    gemm2_kernel<<<1280, 256, 0, stream>>>(hbuf, W2, as2c, ad2c, h2, asrc2, adst2);
    agg2_kernel<<<(NN + 3) / 4, 256, 0, stream>>>(h2, asrc2, adst2, ei, off, eids, b2, outF, outL);
}

// Round 2
// 767.039 us; speedup vs baseline: 1.3827x; 1.3827x over previous
//
#include <hip/hip_runtime.h>
#include <hip/hip_bf16.h>
#include <math.h>

#define NN 50000
#define EE 800000
#define ET 850000   // EE + NN self loops
#define F1 256      // NHEAD*HID
#define NHEAD 8
#define HID 32
#define NCLASS 40
#define NEG 0.2f

__device__ __forceinline__ int clampN(int v) {
    return v < 0 ? 0 : (v >= NN ? NN - 1 : v);
}

// ---------------- CSR construction ----------------
__global__ __launch_bounds__(256) void hist_kernel(const int* __restrict__ ei, int* __restrict__ deg) {
    int t = blockIdx.x * 256 + threadIdx.x;
    if (t >= ET) return;
    int d = (t < EE) ? ei[EE + t] : (t - EE);
    d = clampN(d);
    atomicAdd(&deg[d], 1);
}

__global__ __launch_bounds__(256) void scan1_kernel(const int* __restrict__ deg, int* __restrict__ off, int* __restrict__ bsum) {
    __shared__ int lds[256];
    int b = blockIdx.x, tid = threadIdx.x;
    int base = b * 1024 + tid * 4;
    int v0 = (base + 0 < NN) ? deg[base + 0] : 0;
    int v1 = (base + 1 < NN) ? deg[base + 1] : 0;
    int v2 = (base + 2 < NN) ? deg[base + 2] : 0;
    int v3 = (base + 3 < NN) ? deg[base + 3] : 0;
    int s1 = v0 + v1, s2 = s1 + v2, s3 = s2 + v3;
    lds[tid] = s3;
    __syncthreads();
    for (int o = 1; o < 256; o <<= 1) {
        int t = (tid >= o) ? lds[tid - o] : 0;
        __syncthreads();
        if (tid >= o) lds[tid] += t;
        __syncthreads();
    }
    int excl = tid ? lds[tid - 1] : 0;
    if (base + 0 < NN) off[base + 1] = excl + v0;
    if (base + 1 < NN) off[base + 2] = excl + s1;
    if (base + 2 < NN) off[base + 3] = excl + s2;
    if (base + 3 < NN) off[base + 4] = excl + s3;
    if (tid == 255) bsum[b] = lds[255];
}

__global__ __launch_bounds__(256) void scan2_kernel(int* __restrict__ bsum, int nb) {
    __shared__ int lds[256];
    int tid = threadIdx.x;
    lds[tid] = (tid < nb) ? bsum[tid] : 0;
    __syncthreads();
    for (int o = 1; o < 256; o <<= 1) {
        int t = (tid >= o) ? lds[tid - o] : 0;
        __syncthreads();
        if (tid >= o) lds[tid] += t;
        __syncthreads();
    }
    if (tid < nb) bsum[tid] = lds[tid];
}

__global__ __launch_bounds__(256) void scan3_kernel(int* __restrict__ off, const int* __restrict__ bsum) {
    int b = blockIdx.x, tid = threadIdx.x;
    if (b == 0 && tid == 0) off[0] = 0;
    if (b == 0) return;
    int add = bsum[b - 1];
    int base = b * 1024 + tid * 4;
    #pragma unroll
    for (int i = 0; i < 4; ++i) {
        if (base + i < NN) off[base + i + 1] += add;
    }
}

// scatter: store SOURCE NODE directly in CSR slot (no edge-id indirection)
__global__ __launch_bounds__(256) void scatter_kernel(const int* __restrict__ ei, const int* __restrict__ off,
                                                      int* __restrict__ cursor, int* __restrict__ esrc) {
    int t = blockIdx.x * 256 + threadIdx.x;
    if (t >= ET) return;
    int s, d;
    if (t < EE) { s = ei[t]; d = ei[EE + t]; }
    else        { s = t - EE; d = t - EE; }
    s = clampN(s); d = clampN(d);
    int p = off[d] + atomicAdd(&cursor[d], 1);
    esrc[p] = s;
}

// ---------------- GEMM1: h1 = x @ W1  [50000,256]x[256,256] fp32 ----------------
__global__ __launch_bounds__(256) void gemm1_kernel(const float* __restrict__ A, const float* __restrict__ B,
                                                    float* __restrict__ C) {
    __shared__ __align__(16) float As[16][68];
    __shared__ __align__(16) float Bs[16][68];
    int tid = threadIdx.x;
    int bx = blockIdx.x, by = blockIdx.y;
    int tx = tid & 15, ty = tid >> 4;
    int row0 = by * 64;
    float acc[4][4] = {};
    int lm = tid >> 2;          // A tile row 0..63
    int lk = (tid & 3) * 4;     // A k offset
    int bk = tid >> 4;          // B tile k row 0..15
    int bn = (tid & 15) * 4;    // B tile col offset
    for (int k0 = 0; k0 < 256; k0 += 16) {
        int ar = row0 + lm;
        float4 av = make_float4(0.f, 0.f, 0.f, 0.f);
        if (ar < NN) av = *(const float4*)(A + (size_t)ar * 256 + k0 + lk);
        As[lk + 0][lm] = av.x;
        As[lk + 1][lm] = av.y;
        As[lk + 2][lm] = av.z;
        As[lk + 3][lm] = av.w;
        float4 bv = *(const float4*)(B + (size_t)(k0 + bk) * 256 + bx * 64 + bn);
        *(float4*)(&Bs[bk][bn]) = bv;
        __syncthreads();
        #pragma unroll
        for (int k = 0; k < 16; ++k) {
            float4 a4 = *(const float4*)(&As[k][ty * 4]);
            float4 b4 = *(const float4*)(&Bs[k][tx * 4]);
            float a[4] = {a4.x, a4.y, a4.z, a4.w};
            float b[4] = {b4.x, b4.y, b4.z, b4.w};
            #pragma unroll
            for (int i = 0; i < 4; ++i)
                #pragma unroll
                for (int j = 0; j < 4; ++j)
                    acc[i][j] += a[i] * b[j];
        }
        __syncthreads();
    }
    #pragma unroll
    for (int i = 0; i < 4; ++i) {
        int r = row0 + ty * 4 + i;
        if (r < NN) {
            float4 o = make_float4(acc[i][0], acc[i][1], acc[i][2], acc[i][3]);
            *(float4*)(C + (size_t)r * 256 + bx * 64 + tx * 4) = o;
        }
    }
}

// ---------------- attention logits layer 1 ----------------
__global__ __launch_bounds__(256) void alpha1_kernel(const float* __restrict__ h1, const float* __restrict__ as,
                                                     const float* __restrict__ ad, float* __restrict__ o_s,
                                                     float* __restrict__ o_d) {
    int n = blockIdx.x;
    int t = threadIdx.x;
    float v = h1[(size_t)n * 256 + t];
    float ps = v * as[t];
    float pd = v * ad[t];
    for (int o = 16; o; o >>= 1) {
        ps += __shfl_down(ps, o, 32);
        pd += __shfl_down(pd, o, 32);
    }
    if ((t & 31) == 0) {
        o_s[n * 8 + (t >> 5)] = ps;
        o_d[n * 8 + (t >> 5)] = pd;
    }
}

// ---------------- layer-1 aggregation: wave per dst, single-pass online softmax ----------------
__global__ __launch_bounds__(256) void agg1_kernel(const float* __restrict__ h1, const float* __restrict__ asrc,
                                                   const float* __restrict__ adst, const int* __restrict__ esrc,
                                                   const int* __restrict__ off,
                                                   const float* __restrict__ b1, float* __restrict__ hout) {
    int wid = blockIdx.x * 4 + (threadIdx.x >> 6);
    if (wid >= NN) return;
    int lane = threadIdx.x & 63;
    int hh = lane >> 3;       // head for attention (8 lanes per head)
    int c0 = lane * 4;        // 4 channels owned by this lane
    int d = wid;
    float adh = adst[d * 8 + hh];
    int e0 = off[d], e1 = off[d + 1];

    float m = -INFINITY, s = 0.f;
    float ax = 0.f, ay = 0.f, az = 0.f, aw = 0.f;

    for (int base = e0; base < e1; base += 64) {
        int cnt = e1 - base; if (cnt > 64) cnt = 64;
        // one coalesced load covers the next 64 edge sources
        int snv = esrc[base + (lane < cnt ? lane : cnt - 1)];
        // software pipeline: prefetch edge j+1 while computing edge j
        int sn = __shfl(snv, 0);
        float aP = asrc[sn * 8 + hh];
        float4 hP = *(const float4*)(h1 + (size_t)sn * 256 + c0);
        for (int j = 0; j < cnt; ++j) {
            float aC = aP; float4 hC = hP;
            if (j + 1 < cnt) {
                int sn2 = __shfl(snv, j + 1);
                aP = asrc[sn2 * 8 + hh];
                hP = *(const float4*)(h1 + (size_t)sn2 * 256 + c0);
            }
            float e = aC + adh;
            e = (e >= 0.f) ? e : NEG * e;
            float mn = fmaxf(m, e);
            float r = __expf(m - mn);     // first iter: exp(-inf)=0, zeroes stale acc
            float w = __expf(e - mn);
            s = s * r + w;
            ax = ax * r + w * hC.x;
            ay = ay * r + w * hC.y;
            az = az * r + w * hC.z;
            aw = aw * r + w * hC.w;
            m = mn;
        }
    }
    float inv = 1.f / (s + 1e-16f);
    float4 b = *(const float4*)(b1 + c0);
    float vx = ax * inv + b.x, vy = ay * inv + b.y, vz = az * inv + b.z, vw = aw * inv + b.w;
    float4 o;
    o.x = (vx > 0.f) ? vx : expm1f(vx);
    o.y = (vy > 0.f) ? vy : expm1f(vy);
    o.z = (vz > 0.f) ? vz : expm1f(vz);
    o.w = (vw > 0.f) ? vw : expm1f(vw);
    *(float4*)(hout + (size_t)d * 256 + c0) = o;
}

// ---------------- GEMM2 + attention logits layer 2 ----------------
__global__ __launch_bounds__(256) void gemm2_kernel(const float* __restrict__ h, const float* __restrict__ W2,
                                                    const float* __restrict__ at_s, const float* __restrict__ at_d,
                                                    float* __restrict__ h2, float* __restrict__ as2,
                                                    float* __restrict__ ad2) {
    __shared__ __align__(16) float w2s[256 * 40];
    for (int i = threadIdx.x; i < 256 * 40; i += 256) w2s[i] = W2[i];
    __syncthreads();
    int lane = threadIdx.x & 63;
    int c = lane;
    int stride = gridDim.x * 4;
    for (int wid = blockIdx.x * 4 + (threadIdx.x >> 6); wid < NN; wid += stride) {
        const float* hr = h + (size_t)wid * 256;
        float acc = 0.f;
        #pragma unroll 4
        for (int k = 0; k < 256; k += 4) {
            float4 hv = *(const float4*)(hr + k);
            if (c < NCLASS) {
                acc += hv.x * w2s[(k + 0) * 40 + c];
                acc += hv.y * w2s[(k + 1) * 40 + c];
                acc += hv.z * w2s[(k + 2) * 40 + c];
                acc += hv.w * w2s[(k + 3) * 40 + c];
            }
        }
        float v = (c < NCLASS) ? acc : 0.f;
        if (c < NCLASS) h2[(size_t)wid * 40 + c] = v;
        float ps = (c < NCLASS) ? v * at_s[c] : 0.f;
        float pd = (c < NCLASS) ? v * at_d[c] : 0.f;
        for (int o = 32; o; o >>= 1) {
            ps += __shfl_xor(ps, o);
            pd += __shfl_xor(pd, o);
        }
        if (lane == 0) {
            as2[wid] = ps;
            ad2[wid] = pd;
        }
    }
}

// ---------------- layer-2 aggregation + bias + log_softmax (single-pass) ----------------
__global__ __launch_bounds__(256) void agg2_kernel(const float* __restrict__ h2, const float* __restrict__ asrc,
                                                   const float* __restrict__ adst, const int* __restrict__ esrc,
                                                   const int* __restrict__ off,
                                                   const float* __restrict__ b2, float* __restrict__ outF,
                                                   float* __restrict__ outL) {
    int wid = blockIdx.x * 4 + (threadIdx.x >> 6);
    if (wid >= NN) return;
    int lane = threadIdx.x & 63;
    int c = lane;
    int d = wid;
    float adh = adst[d];
    int e0 = off[d], e1 = off[d + 1];

    float m = -INFINITY, s = 0.f, acc = 0.f;

    for (int base = e0; base < e1; base += 64) {
        int cnt = e1 - base; if (cnt > 64) cnt = 64;
        int snv = esrc[base + (lane < cnt ? lane : cnt - 1)];
        int sn = __shfl(snv, 0);
        float aP = asrc[sn];
        float hP = (c < NCLASS) ? h2[(size_t)sn * 40 + c] : 0.f;
        for (int j = 0; j < cnt; ++j) {
            float aC = aP; float hC = hP;
            if (j + 1 < cnt) {
                int sn2 = __shfl(snv, j + 1);
                aP = asrc[sn2];
                hP = (c < NCLASS) ? h2[(size_t)sn2 * 40 + c] : 0.f;
            }
            float e = aC + adh;
            e = (e >= 0.f) ? e : NEG * e;
            float mn = fmaxf(m, e);
            float r = __expf(m - mn);
            float w = __expf(e - mn);
            s = s * r + w;
            acc = acc * r + w * hC;
            m = mn;
        }
    }
    float inv = 1.f / (s + 1e-16f);
    float fin = (c < NCLASS) ? (acc * inv + b2[c]) : -INFINITY;
    if (c < NCLASS) outF[(size_t)d * 40 + c] = fin;
    // log_softmax across 40 classes
    float mx = fin;
    for (int o = 32; o; o >>= 1) mx = fmaxf(mx, __shfl_xor(mx, o));
    float ex = (c < NCLASS) ? __expf(fin - mx) : 0.f;
    float sm = ex;
    for (int o = 32; o; o >>= 1) sm += __shfl_xor(sm, o);
    if (c < NCLASS) outL[(size_t)d * 40 + c] = fin - mx - __logf(sm);
}

extern "C" void kernel_launch(void* const* d_in, const int* in_sizes, int n_in,
                              void* d_out, int out_size, void* d_ws, size_t ws_size,
                              hipStream_t stream) {
    const float* x   = (const float*)d_in[0];
    const int*   ei  = (const int*)d_in[1];
    const float* W1  = (const float*)d_in[3];
    const float* as1 = (const float*)d_in[4];
    const float* ad1 = (const float*)d_in[5];
    const float* b1  = (const float*)d_in[6];
    const float* W2  = (const float*)d_in[7];
    const float* as2c = (const float*)d_in[8];
    const float* ad2c = (const float*)d_in[9];
    const float* b2  = (const float*)d_in[10];

    float* outF = (float*)d_out;
    float* outL = outF + (size_t)NN * NCLASS;

    char* w = (char*)d_ws;
    auto alloc = [&](size_t bytes) {
        void* p = (void*)w;
        w += (bytes + 255) & ~(size_t)255;
        return p;
    };
    float* h1    = (float*)alloc((size_t)NN * 256 * 4);
    float* hbuf  = (float*)alloc((size_t)NN * 256 * 4);
    float* h2    = (float*)alloc((size_t)NN * 40 * 4);
    float* asrc1 = (float*)alloc((size_t)NN * 8 * 4);
    float* adst1 = (float*)alloc((size_t)NN * 8 * 4);
    float* asrc2 = (float*)alloc((size_t)NN * 4);
    float* adst2 = (float*)alloc((size_t)NN * 4);
    int* deg    = (int*)alloc((size_t)NN * 4);
    int* off    = (int*)alloc((size_t)(NN + 1) * 4);
    int* cursor = (int*)alloc((size_t)NN * 4);
    int* esrc   = (int*)alloc((size_t)ET * 4);
    int* bsum   = (int*)alloc(64 * 4);

    const int NB_SCAN = (NN + 1023) / 1024;  // 49

    hipMemsetAsync(deg, 0, (size_t)NN * 4, stream);
    hipMemsetAsync(cursor, 0, (size_t)NN * 4, stream);

    hist_kernel<<<(ET + 255) / 256, 256, 0, stream>>>(ei, deg);
    scan1_kernel<<<NB_SCAN, 256, 0, stream>>>(deg, off, bsum);
    scan2_kernel<<<1, 256, 0, stream>>>(bsum, NB_SCAN);
    scan3_kernel<<<NB_SCAN, 256, 0, stream>>>(off, bsum);
    scatter_kernel<<<(ET + 255) / 256, 256, 0, stream>>>(ei, off, cursor, esrc);

    gemm1_kernel<<<dim3(4, (NN + 63) / 64), 256, 0, stream>>>(x, W1, h1);
    alpha1_kernel<<<NN, 256, 0, stream>>>(h1, as1, ad1, asrc1, adst1);
    agg1_kernel<<<(NN + 3) / 4, 256, 0, stream>>>(h1, asrc1, adst1, esrc, off, b1, hbuf);
    gemm2_kernel<<<1280, 256, 0, stream>>>(hbuf, W2, as2c, ad2c, h2, asrc2, adst2);
    agg2_kernel<<<(NN + 3) / 4, 256, 0, stream>>>(h2, asrc2, adst2, esrc, off, b2, outF, outL);
}

// Round 3
// 540.338 us; speedup vs baseline: 1.9628x; 1.4196x over previous
//
#include <hip/hip_runtime.h>
#include <hip/hip_bf16.h>
#include <math.h>

#define NN 50000
#define EE 800000
#define ET 850000   // EE + NN self loops
#define F1 256      // NHEAD*HID
#define NHEAD 8
#define HID 32
#define NCLASS 40
#define NEG 0.2f

__device__ __forceinline__ int clampN(int v) {
    return v < 0 ? 0 : (v >= NN ? NN - 1 : v);
}

// ---------------- CSR construction ----------------
__global__ __launch_bounds__(256) void hist_kernel(const int* __restrict__ ei, int* __restrict__ deg) {
    int t = blockIdx.x * 256 + threadIdx.x;
    if (t >= ET) return;
    int d = (t < EE) ? ei[EE + t] : (t - EE);
    d = clampN(d);
    atomicAdd(&deg[d], 1);
}

__global__ __launch_bounds__(256) void scan1_kernel(const int* __restrict__ deg, int* __restrict__ off, int* __restrict__ bsum) {
    __shared__ int lds[256];
    int b = blockIdx.x, tid = threadIdx.x;
    int base = b * 1024 + tid * 4;
    int v0 = (base + 0 < NN) ? deg[base + 0] : 0;
    int v1 = (base + 1 < NN) ? deg[base + 1] : 0;
    int v2 = (base + 2 < NN) ? deg[base + 2] : 0;
    int v3 = (base + 3 < NN) ? deg[base + 3] : 0;
    int s1 = v0 + v1, s2 = s1 + v2, s3 = s2 + v3;
    lds[tid] = s3;
    __syncthreads();
    for (int o = 1; o < 256; o <<= 1) {
        int t = (tid >= o) ? lds[tid - o] : 0;
        __syncthreads();
        if (tid >= o) lds[tid] += t;
        __syncthreads();
    }
    int excl = tid ? lds[tid - 1] : 0;
    if (base + 0 < NN) off[base + 1] = excl + v0;
    if (base + 1 < NN) off[base + 2] = excl + s1;
    if (base + 2 < NN) off[base + 3] = excl + s2;
    if (base + 3 < NN) off[base + 4] = excl + s3;
    if (tid == 255) bsum[b] = lds[255];
}

__global__ __launch_bounds__(256) void scan2_kernel(int* __restrict__ bsum, int nb) {
    __shared__ int lds[256];
    int tid = threadIdx.x;
    lds[tid] = (tid < nb) ? bsum[tid] : 0;
    __syncthreads();
    for (int o = 1; o < 256; o <<= 1) {
        int t = (tid >= o) ? lds[tid - o] : 0;
        __syncthreads();
        if (tid >= o) lds[tid] += t;
        __syncthreads();
    }
    if (tid < nb) bsum[tid] = lds[tid];
}

__global__ __launch_bounds__(256) void scan3_kernel(int* __restrict__ off, const int* __restrict__ bsum) {
    int b = blockIdx.x, tid = threadIdx.x;
    if (b == 0 && tid == 0) off[0] = 0;
    if (b == 0) return;
    int add = bsum[b - 1];
    int base = b * 1024 + tid * 4;
    #pragma unroll
    for (int i = 0; i < 4; ++i) {
        if (base + i < NN) off[base + i + 1] += add;
    }
}

// scatter: store SOURCE NODE directly in CSR slot (no edge-id indirection)
__global__ __launch_bounds__(256) void scatter_kernel(const int* __restrict__ ei, const int* __restrict__ off,
                                                      int* __restrict__ cursor, int* __restrict__ esrc) {
    int t = blockIdx.x * 256 + threadIdx.x;
    if (t >= ET) return;
    int s, d;
    if (t < EE) { s = ei[t]; d = ei[EE + t]; }
    else        { s = t - EE; d = t - EE; }
    s = clampN(s); d = clampN(d);
    int p = off[d] + atomicAdd(&cursor[d], 1);
    esrc[p] = s;
}

// ---------------- GEMM1: h1 = x @ W1  [50000,256]x[256,256] fp32 ----------------
__global__ __launch_bounds__(256) void gemm1_kernel(const float* __restrict__ A, const float* __restrict__ B,
                                                    float* __restrict__ C) {
    __shared__ __align__(16) float As[16][68];
    __shared__ __align__(16) float Bs[16][68];
    int tid = threadIdx.x;
    int bx = blockIdx.x, by = blockIdx.y;
    int tx = tid & 15, ty = tid >> 4;
    int row0 = by * 64;
    float acc[4][4] = {};
    int lm = tid >> 2;          // A tile row 0..63
    int lk = (tid & 3) * 4;     // A k offset
    int bk = tid >> 4;          // B tile k row 0..15
    int bn = (tid & 15) * 4;    // B tile col offset
    for (int k0 = 0; k0 < 256; k0 += 16) {
        int ar = row0 + lm;
        float4 av = make_float4(0.f, 0.f, 0.f, 0.f);
        if (ar < NN) av = *(const float4*)(A + (size_t)ar * 256 + k0 + lk);
        As[lk + 0][lm] = av.x;
        As[lk + 1][lm] = av.y;
        As[lk + 2][lm] = av.z;
        As[lk + 3][lm] = av.w;
        float4 bv = *(const float4*)(B + (size_t)(k0 + bk) * 256 + bx * 64 + bn);
        *(float4*)(&Bs[bk][bn]) = bv;
        __syncthreads();
        #pragma unroll
        for (int k = 0; k < 16; ++k) {
            float4 a4 = *(const float4*)(&As[k][ty * 4]);
            float4 b4 = *(const float4*)(&Bs[k][tx * 4]);
            float a[4] = {a4.x, a4.y, a4.z, a4.w};
            float b[4] = {b4.x, b4.y, b4.z, b4.w};
            #pragma unroll
            for (int i = 0; i < 4; ++i)
                #pragma unroll
                for (int j = 0; j < 4; ++j)
                    acc[i][j] += a[i] * b[j];
        }
        __syncthreads();
    }
    #pragma unroll
    for (int i = 0; i < 4; ++i) {
        int r = row0 + ty * 4 + i;
        if (r < NN) {
            float4 o = make_float4(acc[i][0], acc[i][1], acc[i][2], acc[i][3]);
            *(float4*)(C + (size_t)r * 256 + bx * 64 + tx * 4) = o;
        }
    }
}

// ---------------- attention logits layer 1 ----------------
__global__ __launch_bounds__(256) void alpha1_kernel(const float* __restrict__ h1, const float* __restrict__ as,
                                                     const float* __restrict__ ad, float* __restrict__ o_s,
                                                     float* __restrict__ o_d) {
    int n = blockIdx.x;
    int t = threadIdx.x;
    float v = h1[(size_t)n * 256 + t];
    float ps = v * as[t];
    float pd = v * ad[t];
    for (int o = 16; o; o >>= 1) {
        ps += __shfl_down(ps, o, 32);
        pd += __shfl_down(pd, o, 32);
    }
    if ((t & 31) == 0) {
        o_s[n * 8 + (t >> 5)] = ps;
        o_d[n * 8 + (t >> 5)] = pd;
    }
}

// ---------------- layer-1 aggregation: wave per dst, single-pass online softmax ----------------
__global__ __launch_bounds__(256) void agg1_kernel(const float* __restrict__ h1, const float* __restrict__ asrc,
                                                   const float* __restrict__ adst, const int* __restrict__ esrc,
                                                   const int* __restrict__ off,
                                                   const float* __restrict__ b1, float* __restrict__ hout) {
    int wid = blockIdx.x * 4 + (threadIdx.x >> 6);
    if (wid >= NN) return;
    int lane = threadIdx.x & 63;
    int hh = lane >> 3;       // head for attention (8 lanes per head)
    int c0 = lane * 4;        // 4 channels owned by this lane
    int d = wid;
    float adh = adst[d * 8 + hh];
    int e0 = off[d], e1 = off[d + 1];

    float m = -INFINITY, s = 0.f;
    float ax = 0.f, ay = 0.f, az = 0.f, aw = 0.f;

    for (int base = e0; base < e1; base += 64) {
        int cnt = e1 - base; if (cnt > 64) cnt = 64;
        // one coalesced load covers the next 64 edge sources
        int snv = esrc[base + (lane < cnt ? lane : cnt - 1)];
        // software pipeline: prefetch edge j+1 while computing edge j
        int sn = __shfl(snv, 0);
        float aP = asrc[sn * 8 + hh];
        float4 hP = *(const float4*)(h1 + (size_t)sn * 256 + c0);
        for (int j = 0; j < cnt; ++j) {
            float aC = aP; float4 hC = hP;
            if (j + 1 < cnt) {
                int sn2 = __shfl(snv, j + 1);
                aP = asrc[sn2 * 8 + hh];
                hP = *(const float4*)(h1 + (size_t)sn2 * 256 + c0);
            }
            float e = aC + adh;
            e = (e >= 0.f) ? e : NEG * e;
            float mn = fmaxf(m, e);
            float r = __expf(m - mn);     // first iter: exp(-inf)=0, zeroes stale acc
            float w = __expf(e - mn);
            s = s * r + w;
            ax = ax * r + w * hC.x;
            ay = ay * r + w * hC.y;
            az = az * r + w * hC.z;
            aw = aw * r + w * hC.w;
            m = mn;
        }
    }
    float inv = 1.f / (s + 1e-16f);
    float4 b = *(const float4*)(b1 + c0);
    float vx = ax * inv + b.x, vy = ay * inv + b.y, vz = az * inv + b.z, vw = aw * inv + b.w;
    float4 o;
    o.x = (vx > 0.f) ? vx : expm1f(vx);
    o.y = (vy > 0.f) ? vy : expm1f(vy);
    o.z = (vz > 0.f) ? vz : expm1f(vz);
    o.w = (vw > 0.f) ? vw : expm1f(vw);
    *(float4*)(hout + (size_t)d * 256 + c0) = o;
}

// ---------------- GEMM2 (register-tiled) + fused attention logits layer 2 ----------------
// Block: 128 rows x 40 cols. Thread: 4 rows x 5 cols (cols g, g+8, ..., g+32).
// Per k: 1 ds_read_b128 (A, transposed +132-pad tile) + 5 b32 (W2) -> 20 FMAs.
#define G2_TM 128
#define G2_KC 32
__global__ __launch_bounds__(256) void gemm2_kernel(const float* __restrict__ h, const float* __restrict__ W2,
                                                    const float* __restrict__ at_s, const float* __restrict__ at_d,
                                                    float* __restrict__ h2, float* __restrict__ as2,
                                                    float* __restrict__ ad2) {
    __shared__ __align__(16) float w2s[256 * 40];     // 40 KB
    __shared__ __align__(16) float As[G2_KC][132];    // 16.5 KB, stride 132: 16B-aligned rows, conflict-free b128 reads
    int tid = threadIdx.x;
    for (int i = tid; i < 256 * 40; i += 256) w2s[i] = W2[i];
    int g  = tid & 7;    // column group: cols g + 8j, j=0..4
    int rg = tid >> 3;   // row group: rows rg*4 .. rg*4+3  (0..31)
    int row0 = blockIdx.x * G2_TM;
    float acc[4][5] = {};
    float ats[5], atd[5];
    #pragma unroll
    for (int j = 0; j < 5; ++j) { ats[j] = at_s[g + 8 * j]; atd[j] = at_d[g + 8 * j]; }

    for (int k0 = 0; k0 < 256; k0 += G2_KC) {
        __syncthreads();
        // stage A chunk [128 rows x 32 k] transposed into As[k][row]
        #pragma unroll
        for (int i = 0; i < 4; ++i) {
            int id = i * 256 + tid;
            int r  = id >> 3;       // 0..127
            int kq = id & 7;        // float4 index in 32-k chunk
            int rr = row0 + r; if (rr >= NN) rr = NN - 1;
            float4 v = *(const float4*)(h + (size_t)rr * 256 + k0 + kq * 4);
            As[kq * 4 + 0][r] = v.x;
            As[kq * 4 + 1][r] = v.y;
            As[kq * 4 + 2][r] = v.z;
            As[kq * 4 + 3][r] = v.w;
        }
        __syncthreads();
        #pragma unroll 4
        for (int k = 0; k < G2_KC; ++k) {
            float4 a = *(const float4*)(&As[k][rg * 4]);
            float w[5];
            #pragma unroll
            for (int j = 0; j < 5; ++j) w[j] = w2s[(k0 + k) * 40 + g + 8 * j];
            float av[4] = {a.x, a.y, a.z, a.w};
            #pragma unroll
            for (int r = 0; r < 4; ++r)
                #pragma unroll
                for (int j = 0; j < 5; ++j)
                    acc[r][j] += av[r] * w[j];
        }
    }

    // epilogue: store h2 + fused alpha2 (reduce over the 8 g-lanes sharing a row)
    #pragma unroll
    for (int r = 0; r < 4; ++r) {
        int row = row0 + rg * 4 + r;
        float ps = 0.f, pd = 0.f;
        #pragma unroll
        for (int j = 0; j < 5; ++j) {
            ps += acc[r][j] * ats[j];
            pd += acc[r][j] * atd[j];
        }
        ps += __shfl_xor(ps, 1); pd += __shfl_xor(pd, 1);
        ps += __shfl_xor(ps, 2); pd += __shfl_xor(pd, 2);
        ps += __shfl_xor(ps, 4); pd += __shfl_xor(pd, 4);
        if (row < NN) {
            #pragma unroll
            for (int j = 0; j < 5; ++j) h2[(size_t)row * 40 + g + 8 * j] = acc[r][j];
            if (g == 0) { as2[row] = ps; ad2[row] = pd; }
        }
    }
}

// ---------------- layer-2 aggregation + bias + log_softmax (single-pass) ----------------
__global__ __launch_bounds__(256) void agg2_kernel(const float* __restrict__ h2, const float* __restrict__ asrc,
                                                   const float* __restrict__ adst, const int* __restrict__ esrc,
                                                   const int* __restrict__ off,
                                                   const float* __restrict__ b2, float* __restrict__ outF,
                                                   float* __restrict__ outL) {
    int wid = blockIdx.x * 4 + (threadIdx.x >> 6);
    if (wid >= NN) return;
    int lane = threadIdx.x & 63;
    int c = lane;
    int d = wid;
    float adh = adst[d];
    int e0 = off[d], e1 = off[d + 1];

    float m = -INFINITY, s = 0.f, acc = 0.f;

    for (int base = e0; base < e1; base += 64) {
        int cnt = e1 - base; if (cnt > 64) cnt = 64;
        int snv = esrc[base + (lane < cnt ? lane : cnt - 1)];
        int sn = __shfl(snv, 0);
        float aP = asrc[sn];
        float hP = (c < NCLASS) ? h2[(size_t)sn * 40 + c] : 0.f;
        for (int j = 0; j < cnt; ++j) {
            float aC = aP; float hC = hP;
            if (j + 1 < cnt) {
                int sn2 = __shfl(snv, j + 1);
                aP = asrc[sn2];
                hP = (c < NCLASS) ? h2[(size_t)sn2 * 40 + c] : 0.f;
            }
            float e = aC + adh;
            e = (e >= 0.f) ? e : NEG * e;
            float mn = fmaxf(m, e);
            float r = __expf(m - mn);
            float w = __expf(e - mn);
            s = s * r + w;
            acc = acc * r + w * hC;
            m = mn;
        }
    }
    float inv = 1.f / (s + 1e-16f);
    float fin = (c < NCLASS) ? (acc * inv + b2[c]) : -INFINITY;
    if (c < NCLASS) outF[(size_t)d * 40 + c] = fin;
    // log_softmax across 40 classes
    float mx = fin;
    for (int o = 32; o; o >>= 1) mx = fmaxf(mx, __shfl_xor(mx, o));
    float ex = (c < NCLASS) ? __expf(fin - mx) : 0.f;
    float sm = ex;
    for (int o = 32; o; o >>= 1) sm += __shfl_xor(sm, o);
    if (c < NCLASS) outL[(size_t)d * 40 + c] = fin - mx - __logf(sm);
}

extern "C" void kernel_launch(void* const* d_in, const int* in_sizes, int n_in,
                              void* d_out, int out_size, void* d_ws, size_t ws_size,
                              hipStream_t stream) {
    const float* x   = (const float*)d_in[0];
    const int*   ei  = (const int*)d_in[1];
    const float* W1  = (const float*)d_in[3];
    const float* as1 = (const float*)d_in[4];
    const float* ad1 = (const float*)d_in[5];
    const float* b1  = (const float*)d_in[6];
    const float* W2  = (const float*)d_in[7];
    const float* as2c = (const float*)d_in[8];
    const float* ad2c = (const float*)d_in[9];
    const float* b2  = (const float*)d_in[10];

    float* outF = (float*)d_out;
    float* outL = outF + (size_t)NN * NCLASS;

    char* w = (char*)d_ws;
    auto alloc = [&](size_t bytes) {
        void* p = (void*)w;
        w += (bytes + 255) & ~(size_t)255;
        return p;
    };
    float* h1    = (float*)alloc((size_t)NN * 256 * 4);
    float* hbuf  = (float*)alloc((size_t)NN * 256 * 4);
    float* h2    = (float*)alloc((size_t)NN * 40 * 4);
    float* asrc1 = (float*)alloc((size_t)NN * 8 * 4);
    float* adst1 = (float*)alloc((size_t)NN * 8 * 4);
    float* asrc2 = (float*)alloc((size_t)NN * 4);
    float* adst2 = (float*)alloc((size_t)NN * 4);
    int* deg    = (int*)alloc((size_t)NN * 4);
    int* off    = (int*)alloc((size_t)(NN + 1) * 4);
    int* cursor = (int*)alloc((size_t)NN * 4);
    int* esrc   = (int*)alloc((size_t)ET * 4);
    int* bsum   = (int*)alloc(64 * 4);

    const int NB_SCAN = (NN + 1023) / 1024;  // 49

    hipMemsetAsync(deg, 0, (size_t)NN * 4, stream);
    hipMemsetAsync(cursor, 0, (size_t)NN * 4, stream);

    hist_kernel<<<(ET + 255) / 256, 256, 0, stream>>>(ei, deg);
    scan1_kernel<<<NB_SCAN, 256, 0, stream>>>(deg, off, bsum);
    scan2_kernel<<<1, 256, 0, stream>>>(bsum, NB_SCAN);
    scan3_kernel<<<NB_SCAN, 256, 0, stream>>>(off, bsum);
    scatter_kernel<<<(ET + 255) / 256, 256, 0, stream>>>(ei, off, cursor, esrc);

    gemm1_kernel<<<dim3(4, (NN + 63) / 64), 256, 0, stream>>>(x, W1, h1);
    alpha1_kernel<<<NN, 256, 0, stream>>>(h1, as1, ad1, asrc1, adst1);
    agg1_kernel<<<(NN + 3) / 4, 256, 0, stream>>>(h1, asrc1, adst1, esrc, off, b1, hbuf);
    gemm2_kernel<<<(NN + G2_TM - 1) / G2_TM, 256, 0, stream>>>(hbuf, W2, as2c, ad2c, h2, asrc2, adst2);
    agg2_kernel<<<(NN + 3) / 4, 256, 0, stream>>>(h2, asrc2, adst2, esrc, off, b2, outF, outL);
}

// Round 4
// 459.309 us; speedup vs baseline: 2.3090x; 1.1764x over previous
//
#include <hip/hip_runtime.h>
#include <hip/hip_bf16.h>
#include <math.h>

#define NN 50000
#define EE 800000
#define ET 850000   // EE + NN self loops
#define F1 256      // NHEAD*HID
#define NHEAD 8
#define HID 32
#define NCLASS 40
#define NEG 0.2f

__device__ __forceinline__ int clampN(int v) {
    return v < 0 ? 0 : (v >= NN ? NN - 1 : v);
}
__device__ __forceinline__ unsigned short f2bf(float f) {
    __hip_bfloat16 h = __float2bfloat16(f);
    return __builtin_bit_cast(unsigned short, h);
}
__device__ __forceinline__ float bf2f(unsigned short u) {
    return __uint_as_float((unsigned)u << 16);
}

// ---------------- CSR construction ----------------
__global__ __launch_bounds__(256) void hist_kernel(const int* __restrict__ ei, int* __restrict__ deg) {
    int t = blockIdx.x * 256 + threadIdx.x;
    if (t >= ET) return;
    int d = (t < EE) ? ei[EE + t] : (t - EE);
    d = clampN(d);
    atomicAdd(&deg[d], 1);
}

__global__ __launch_bounds__(256) void scan1_kernel(const int* __restrict__ deg, int* __restrict__ off, int* __restrict__ bsum) {
    __shared__ int lds[256];
    int b = blockIdx.x, tid = threadIdx.x;
    int base = b * 1024 + tid * 4;
    int v0 = (base + 0 < NN) ? deg[base + 0] : 0;
    int v1 = (base + 1 < NN) ? deg[base + 1] : 0;
    int v2 = (base + 2 < NN) ? deg[base + 2] : 0;
    int v3 = (base + 3 < NN) ? deg[base + 3] : 0;
    int s1 = v0 + v1, s2 = s1 + v2, s3 = s2 + v3;
    lds[tid] = s3;
    __syncthreads();
    for (int o = 1; o < 256; o <<= 1) {
        int t = (tid >= o) ? lds[tid - o] : 0;
        __syncthreads();
        if (tid >= o) lds[tid] += t;
        __syncthreads();
    }
    int excl = tid ? lds[tid - 1] : 0;
    if (base + 0 < NN) off[base + 1] = excl + v0;
    if (base + 1 < NN) off[base + 2] = excl + s1;
    if (base + 2 < NN) off[base + 3] = excl + s2;
    if (base + 3 < NN) off[base + 4] = excl + s3;
    if (tid == 255) bsum[b] = lds[255];
}

__global__ __launch_bounds__(256) void scan2_kernel(int* __restrict__ bsum, int nb) {
    __shared__ int lds[256];
    int tid = threadIdx.x;
    lds[tid] = (tid < nb) ? bsum[tid] : 0;
    __syncthreads();
    for (int o = 1; o < 256; o <<= 1) {
        int t = (tid >= o) ? lds[tid - o] : 0;
        __syncthreads();
        if (tid >= o) lds[tid] += t;
        __syncthreads();
    }
    if (tid < nb) bsum[tid] = lds[tid];
}

__global__ __launch_bounds__(256) void scan3_kernel(int* __restrict__ off, const int* __restrict__ bsum) {
    int b = blockIdx.x, tid = threadIdx.x;
    if (b == 0 && tid == 0) off[0] = 0;
    if (b == 0) return;
    int add = bsum[b - 1];
    int base = b * 1024 + tid * 4;
    #pragma unroll
    for (int i = 0; i < 4; ++i) {
        if (base + i < NN) off[base + i + 1] += add;
    }
}

__global__ __launch_bounds__(256) void scatter_kernel(const int* __restrict__ ei, const int* __restrict__ off,
                                                      int* __restrict__ cursor, int* __restrict__ esrc) {
    int t = blockIdx.x * 256 + threadIdx.x;
    if (t >= ET) return;
    int s, d;
    if (t < EE) { s = ei[t]; d = ei[EE + t]; }
    else        { s = t - EE; d = t - EE; }
    s = clampN(s); d = clampN(d);
    int p = off[d] + atomicAdd(&cursor[d], 1);
    esrc[p] = s;
}

// ---------------- GEMM1: h1 = x @ W1  [50000,256]x[256,256] fp32, bf16 output ----------------
__global__ __launch_bounds__(256) void gemm1_kernel(const float* __restrict__ A, const float* __restrict__ B,
                                                    unsigned short* __restrict__ h1b) {
    __shared__ __align__(16) float As[16][68];
    __shared__ __align__(16) float Bs[16][68];
    int tid = threadIdx.x;
    int bx = blockIdx.x, by = blockIdx.y;
    int tx = tid & 15, ty = tid >> 4;
    int row0 = by * 64;
    float acc[4][4] = {};
    int lm = tid >> 2;          // A tile row 0..63
    int lk = (tid & 3) * 4;     // A k offset
    int bk = tid >> 4;          // B tile k row 0..15
    int bn = (tid & 15) * 4;    // B tile col offset
    for (int k0 = 0; k0 < 256; k0 += 16) {
        int ar = row0 + lm;
        float4 av = make_float4(0.f, 0.f, 0.f, 0.f);
        if (ar < NN) av = *(const float4*)(A + (size_t)ar * 256 + k0 + lk);
        As[lk + 0][lm] = av.x;
        As[lk + 1][lm] = av.y;
        As[lk + 2][lm] = av.z;
        As[lk + 3][lm] = av.w;
        float4 bv = *(const float4*)(B + (size_t)(k0 + bk) * 256 + bx * 64 + bn);
        *(float4*)(&Bs[bk][bn]) = bv;
        __syncthreads();
        #pragma unroll
        for (int k = 0; k < 16; ++k) {
            float4 a4 = *(const float4*)(&As[k][ty * 4]);
            float4 b4 = *(const float4*)(&Bs[k][tx * 4]);
            float a[4] = {a4.x, a4.y, a4.z, a4.w};
            float b[4] = {b4.x, b4.y, b4.z, b4.w};
            #pragma unroll
            for (int i = 0; i < 4; ++i)
                #pragma unroll
                for (int j = 0; j < 4; ++j)
                    acc[i][j] += a[i] * b[j];
        }
        __syncthreads();
    }
    #pragma unroll
    for (int i = 0; i < 4; ++i) {
        int r = row0 + ty * 4 + i;
        if (r < NN) {
            ushort4 o;
            o.x = f2bf(acc[i][0]);
            o.y = f2bf(acc[i][1]);
            o.z = f2bf(acc[i][2]);
            o.w = f2bf(acc[i][3]);
            *(ushort4*)(h1b + (size_t)r * 256 + bx * 64 + tx * 4) = o;
        }
    }
}

// ---------------- attention logits layer 1 (wave per node, bf16 h1) ----------------
__global__ __launch_bounds__(256) void alpha1_kernel(const unsigned short* __restrict__ h1b,
                                                     const float* __restrict__ as, const float* __restrict__ ad,
                                                     float* __restrict__ o_s, float* __restrict__ o_d) {
    int wid = blockIdx.x * 4 + (threadIdx.x >> 6);
    if (wid >= NN) return;
    int lane = threadIdx.x & 63;
    int c0 = lane * 4;
    ushort4 hv = *(const ushort4*)(h1b + (size_t)wid * 256 + c0);
    float4 a = *(const float4*)(as + c0);
    float4 dd = *(const float4*)(ad + c0);
    float hx = bf2f(hv.x), hy = bf2f(hv.y), hz = bf2f(hv.z), hw = bf2f(hv.w);
    float ps = hx * a.x + hy * a.y + hz * a.z + hw * a.w;
    float pd = hx * dd.x + hy * dd.y + hz * dd.z + hw * dd.w;
    ps += __shfl_xor(ps, 1); pd += __shfl_xor(pd, 1);
    ps += __shfl_xor(ps, 2); pd += __shfl_xor(pd, 2);
    ps += __shfl_xor(ps, 4); pd += __shfl_xor(pd, 4);
    if ((lane & 7) == 0) {
        o_s[wid * 8 + (lane >> 3)] = ps;
        o_d[wid * 8 + (lane >> 3)] = pd;
    }
}

// ---------------- layer-1 aggregation: wave per dst, bf16 gather, single-pass online softmax ----------------
__global__ __launch_bounds__(256) void agg1_kernel(const unsigned short* __restrict__ h1b, const float* __restrict__ asrc,
                                                   const float* __restrict__ adst, const int* __restrict__ esrc,
                                                   const int* __restrict__ off,
                                                   const float* __restrict__ b1, float* __restrict__ hout) {
    int wid = blockIdx.x * 4 + (threadIdx.x >> 6);
    if (wid >= NN) return;
    int lane = threadIdx.x & 63;
    int hh = lane >> 3;       // head (8 lanes per head)
    int c0 = lane * 4;        // 4 channels owned by this lane
    float adh = adst[wid * 8 + hh];
    int e0 = off[wid], e1 = off[wid + 1];
    const char* hbase = (const char*)h1b + ((size_t)c0 << 1);

    float m = -INFINITY, s = 0.f;
    float ax = 0.f, ay = 0.f, az = 0.f, aw = 0.f;

    for (int base = e0; base < e1; base += 64) {
        int cnt = e1 - base; if (cnt > 64) cnt = 64;
        int snv = esrc[base + (lane < cnt ? lane : cnt - 1)];
        int sn = __shfl(snv, 0);
        float aP = asrc[sn * 8 + hh];
        ushort4 hP = *(const ushort4*)(hbase + ((size_t)sn << 9));
        for (int j = 0; j < cnt; ++j) {
            float aC = aP; ushort4 hC = hP;
            if (j + 1 < cnt) {
                int sn2 = __shfl(snv, j + 1);
                aP = asrc[sn2 * 8 + hh];
                hP = *(const ushort4*)(hbase + ((size_t)sn2 << 9));
            }
            float e = aC + adh;
            e = (e >= 0.f) ? e : NEG * e;
            float mn = fmaxf(m, e);
            float r = __expf(m - mn);     // first iter: exp(-inf)=0
            float w = __expf(e - mn);
            s = s * r + w;
            ax = ax * r + w * bf2f(hC.x);
            ay = ay * r + w * bf2f(hC.y);
            az = az * r + w * bf2f(hC.z);
            aw = aw * r + w * bf2f(hC.w);
            m = mn;
        }
    }
    float inv = 1.f / (s + 1e-16f);
    float4 b = *(const float4*)(b1 + c0);
    float vx = ax * inv + b.x, vy = ay * inv + b.y, vz = az * inv + b.z, vw = aw * inv + b.w;
    float4 o;
    o.x = (vx > 0.f) ? vx : expm1f(vx);
    o.y = (vy > 0.f) ? vy : expm1f(vy);
    o.z = (vz > 0.f) ? vz : expm1f(vz);
    o.w = (vw > 0.f) ? vw : expm1f(vw);
    *(float4*)(hout + (size_t)wid * 256 + c0) = o;
}

// ---------------- GEMM2 (register-tiled) + fused attention logits layer 2, bf16 h2 out ----------------
#define G2_TM 128
#define G2_KC 32
__global__ __launch_bounds__(256) void gemm2_kernel(const float* __restrict__ h, const float* __restrict__ W2,
                                                    const float* __restrict__ at_s, const float* __restrict__ at_d,
                                                    unsigned short* __restrict__ h2b, float* __restrict__ as2,
                                                    float* __restrict__ ad2) {
    __shared__ __align__(16) float w2s[256 * 40];     // 40 KB
    __shared__ __align__(16) float As[G2_KC][132];    // 16.5 KB
    int tid = threadIdx.x;
    for (int i = tid; i < 256 * 40; i += 256) w2s[i] = W2[i];
    int g  = tid & 7;    // column group: cols g + 8j, j=0..4
    int rg = tid >> 3;   // row group: rows rg*4 .. rg*4+3
    int row0 = blockIdx.x * G2_TM;
    float acc[4][5] = {};
    float ats[5], atd[5];
    #pragma unroll
    for (int j = 0; j < 5; ++j) { ats[j] = at_s[g + 8 * j]; atd[j] = at_d[g + 8 * j]; }

    for (int k0 = 0; k0 < 256; k0 += G2_KC) {
        __syncthreads();
        #pragma unroll
        for (int i = 0; i < 4; ++i) {
            int id = i * 256 + tid;
            int r  = id >> 3;
            int kq = id & 7;
            int rr = row0 + r; if (rr >= NN) rr = NN - 1;
            float4 v = *(const float4*)(h + (size_t)rr * 256 + k0 + kq * 4);
            As[kq * 4 + 0][r] = v.x;
            As[kq * 4 + 1][r] = v.y;
            As[kq * 4 + 2][r] = v.z;
            As[kq * 4 + 3][r] = v.w;
        }
        __syncthreads();
        #pragma unroll 4
        for (int k = 0; k < G2_KC; ++k) {
            float4 a = *(const float4*)(&As[k][rg * 4]);
            float w[5];
            #pragma unroll
            for (int j = 0; j < 5; ++j) w[j] = w2s[(k0 + k) * 40 + g + 8 * j];
            float av[4] = {a.x, a.y, a.z, a.w};
            #pragma unroll
            for (int r = 0; r < 4; ++r)
                #pragma unroll
                for (int j = 0; j < 5; ++j)
                    acc[r][j] += av[r] * w[j];
        }
    }

    #pragma unroll
    for (int r = 0; r < 4; ++r) {
        int row = row0 + rg * 4 + r;
        float ps = 0.f, pd = 0.f;
        #pragma unroll
        for (int j = 0; j < 5; ++j) {
            ps += acc[r][j] * ats[j];
            pd += acc[r][j] * atd[j];
        }
        ps += __shfl_xor(ps, 1); pd += __shfl_xor(pd, 1);
        ps += __shfl_xor(ps, 2); pd += __shfl_xor(pd, 2);
        ps += __shfl_xor(ps, 4); pd += __shfl_xor(pd, 4);
        if (row < NN) {
            #pragma unroll
            for (int j = 0; j < 5; ++j) h2b[(size_t)row * 40 + g + 8 * j] = f2bf(acc[r][j]);
            if (g == 0) { as2[row] = ps; ad2[row] = pd; }
        }
    }
}

// ---------------- layer-2 aggregation + bias + log_softmax (bf16 gather, single-pass) ----------------
__global__ __launch_bounds__(256) void agg2_kernel(const unsigned short* __restrict__ h2b, const float* __restrict__ asrc,
                                                   const float* __restrict__ adst, const int* __restrict__ esrc,
                                                   const int* __restrict__ off,
                                                   const float* __restrict__ b2, float* __restrict__ outF,
                                                   float* __restrict__ outL) {
    int wid = blockIdx.x * 4 + (threadIdx.x >> 6);
    if (wid >= NN) return;
    int lane = threadIdx.x & 63;
    int c = lane;
    float adh = adst[wid];
    int e0 = off[wid], e1 = off[wid + 1];
    const char* hbase = (const char*)h2b + ((size_t)(c < NCLASS ? c : 0) << 1);

    float m = -INFINITY, s = 0.f, acc = 0.f;

    for (int base = e0; base < e1; base += 64) {
        int cnt = e1 - base; if (cnt > 64) cnt = 64;
        int snv = esrc[base + (lane < cnt ? lane : cnt - 1)];
        int sn = __shfl(snv, 0);
        float aP = asrc[sn];
        unsigned short hP = *(const unsigned short*)(hbase + (size_t)sn * 80);
        for (int j = 0; j < cnt; ++j) {
            float aC = aP; unsigned short hC = hP;
            if (j + 1 < cnt) {
                int sn2 = __shfl(snv, j + 1);
                aP = asrc[sn2];
                hP = *(const unsigned short*)(hbase + (size_t)sn2 * 80);
            }
            float e = aC + adh;
            e = (e >= 0.f) ? e : NEG * e;
            float mn = fmaxf(m, e);
            float r = __expf(m - mn);
            float w = __expf(e - mn);
            s = s * r + w;
            acc = acc * r + w * bf2f(hC);
            m = mn;
        }
    }
    float inv = 1.f / (s + 1e-16f);
    float fin = (c < NCLASS) ? (acc * inv + b2[c]) : -INFINITY;
    if (c < NCLASS) outF[(size_t)wid * 40 + c] = fin;
    float mx = fin;
    for (int o = 32; o; o >>= 1) mx = fmaxf(mx, __shfl_xor(mx, o));
    float ex = (c < NCLASS) ? __expf(fin - mx) : 0.f;
    float sm = ex;
    for (int o = 32; o; o >>= 1) sm += __shfl_xor(sm, o);
    if (c < NCLASS) outL[(size_t)wid * 40 + c] = fin - mx - __logf(sm);
}

extern "C" void kernel_launch(void* const* d_in, const int* in_sizes, int n_in,
                              void* d_out, int out_size, void* d_ws, size_t ws_size,
                              hipStream_t stream) {
    const float* x   = (const float*)d_in[0];
    const int*   ei  = (const int*)d_in[1];
    const float* W1  = (const float*)d_in[3];
    const float* as1 = (const float*)d_in[4];
    const float* ad1 = (const float*)d_in[5];
    const float* b1  = (const float*)d_in[6];
    const float* W2  = (const float*)d_in[7];
    const float* as2c = (const float*)d_in[8];
    const float* ad2c = (const float*)d_in[9];
    const float* b2  = (const float*)d_in[10];

    float* outF = (float*)d_out;
    float* outL = outF + (size_t)NN * NCLASS;

    char* w = (char*)d_ws;
    auto alloc = [&](size_t bytes) {
        void* p = (void*)w;
        w += (bytes + 255) & ~(size_t)255;
        return p;
    };
    unsigned short* h1b = (unsigned short*)alloc((size_t)NN * 256 * 2);
    float* hbuf  = (float*)alloc((size_t)NN * 256 * 4);
    unsigned short* h2b = (unsigned short*)alloc((size_t)NN * 40 * 2);
    float* asrc1 = (float*)alloc((size_t)NN * 8 * 4);
    float* adst1 = (float*)alloc((size_t)NN * 8 * 4);
    float* asrc2 = (float*)alloc((size_t)NN * 4);
    float* adst2 = (float*)alloc((size_t)NN * 4);
    int* deg    = (int*)alloc((size_t)NN * 4);
    int* off    = (int*)alloc((size_t)(NN + 1) * 4);
    int* cursor = (int*)alloc((size_t)NN * 4);
    int* esrc   = (int*)alloc((size_t)ET * 4);
    int* bsum   = (int*)alloc(64 * 4);

    const int NB_SCAN = (NN + 1023) / 1024;  // 49

    hipMemsetAsync(deg, 0, (size_t)NN * 4, stream);
    hipMemsetAsync(cursor, 0, (size_t)NN * 4, stream);

    hist_kernel<<<(ET + 255) / 256, 256, 0, stream>>>(ei, deg);
    scan1_kernel<<<NB_SCAN, 256, 0, stream>>>(deg, off, bsum);
    scan2_kernel<<<1, 256, 0, stream>>>(bsum, NB_SCAN);
    scan3_kernel<<<NB_SCAN, 256, 0, stream>>>(off, bsum);
    scatter_kernel<<<(ET + 255) / 256, 256, 0, stream>>>(ei, off, cursor, esrc);

    gemm1_kernel<<<dim3(4, (NN + 63) / 64), 256, 0, stream>>>(x, W1, h1b);
    alpha1_kernel<<<(NN + 3) / 4, 256, 0, stream>>>(h1b, as1, ad1, asrc1, adst1);
    agg1_kernel<<<(NN + 3) / 4, 256, 0, stream>>>(h1b, asrc1, adst1, esrc, off, b1, hbuf);
    gemm2_kernel<<<(NN + G2_TM - 1) / G2_TM, 256, 0, stream>>>(hbuf, W2, as2c, ad2c, h2b, asrc2, adst2);
    agg2_kernel<<<(NN + 3) / 4, 256, 0, stream>>>(h2b, asrc2, adst2, esrc, off, b2, outF, outL);
}

// Round 5
// 403.385 us; speedup vs baseline: 2.6292x; 1.1386x over previous
//
#include <hip/hip_runtime.h>
#include <hip/hip_bf16.h>
#include <math.h>

#define NN 50000
#define EE 800000
#define ET 850000   // EE + NN self loops
#define F1 256      // NHEAD*HID
#define NHEAD 8
#define HID 32
#define NCLASS 40
#define NEG 0.2f

typedef __attribute__((ext_vector_type(8))) short short8_t;   // 8 bf16 (4 VGPRs)
typedef __attribute__((ext_vector_type(4))) float float4_t;   // MFMA C/D

__device__ __forceinline__ int clampN(int v) {
    return v < 0 ? 0 : (v >= NN ? NN - 1 : v);
}
__device__ __forceinline__ unsigned short f2bf(float f) {
    __hip_bfloat16 h = __float2bfloat16(f);
    return __builtin_bit_cast(unsigned short, h);
}
__device__ __forceinline__ float bf2f(unsigned short u) {
    return __uint_as_float((unsigned)u << 16);
}

// ---------------- CSR construction ----------------
__global__ __launch_bounds__(256) void hist_kernel(const int* __restrict__ ei, int* __restrict__ deg) {
    int t = blockIdx.x * 256 + threadIdx.x;
    if (t >= ET) return;
    int d = (t < EE) ? ei[EE + t] : (t - EE);
    d = clampN(d);
    atomicAdd(&deg[d], 1);
}

__global__ __launch_bounds__(256) void scan1_kernel(const int* __restrict__ deg, int* __restrict__ off, int* __restrict__ bsum) {
    __shared__ int lds[256];
    int b = blockIdx.x, tid = threadIdx.x;
    int base = b * 1024 + tid * 4;
    int v0 = (base + 0 < NN) ? deg[base + 0] : 0;
    int v1 = (base + 1 < NN) ? deg[base + 1] : 0;
    int v2 = (base + 2 < NN) ? deg[base + 2] : 0;
    int v3 = (base + 3 < NN) ? deg[base + 3] : 0;
    int s1 = v0 + v1, s2 = s1 + v2, s3 = s2 + v3;
    lds[tid] = s3;
    __syncthreads();
    for (int o = 1; o < 256; o <<= 1) {
        int t = (tid >= o) ? lds[tid - o] : 0;
        __syncthreads();
        if (tid >= o) lds[tid] += t;
        __syncthreads();
    }
    int excl = tid ? lds[tid - 1] : 0;
    if (base + 0 < NN) off[base + 1] = excl + v0;
    if (base + 1 < NN) off[base + 2] = excl + s1;
    if (base + 2 < NN) off[base + 3] = excl + s2;
    if (base + 3 < NN) off[base + 4] = excl + s3;
    if (tid == 255) bsum[b] = lds[255];
}

__global__ __launch_bounds__(256) void scan2_kernel(int* __restrict__ bsum, int nb) {
    __shared__ int lds[256];
    int tid = threadIdx.x;
    lds[tid] = (tid < nb) ? bsum[tid] : 0;
    __syncthreads();
    for (int o = 1; o < 256; o <<= 1) {
        int t = (tid >= o) ? lds[tid - o] : 0;
        __syncthreads();
        if (tid >= o) lds[tid] += t;
        __syncthreads();
    }
    if (tid < nb) bsum[tid] = lds[tid];
}

__global__ __launch_bounds__(256) void scan3_kernel(int* __restrict__ off, const int* __restrict__ bsum) {
    int b = blockIdx.x, tid = threadIdx.x;
    if (b == 0 && tid == 0) off[0] = 0;
    if (b == 0) return;
    int add = bsum[b - 1];
    int base = b * 1024 + tid * 4;
    #pragma unroll
    for (int i = 0; i < 4; ++i) {
        if (base + i < NN) off[base + i + 1] += add;
    }
}

__global__ __launch_bounds__(256) void scatter_kernel(const int* __restrict__ ei, const int* __restrict__ off,
                                                      int* __restrict__ cursor, int* __restrict__ esrc) {
    int t = blockIdx.x * 256 + threadIdx.x;
    if (t >= ET) return;
    int s, d;
    if (t < EE) { s = ei[t]; d = ei[EE + t]; }
    else        { s = t - EE; d = t - EE; }
    s = clampN(s); d = clampN(d);
    int p = off[d] + atomicAdd(&cursor[d], 1);
    esrc[p] = s;
}

// ---------------- prep: W1t[272][256] split into bf16 hi/lo ----------------
// rows 0..255: W1^T (col n of W1). rows 256+j: j<8 -> W1[:,h*32:h*32+32]@att_src1[h],
// j>=8 -> same with att_dst1. Folding attention into the GEMM: alpha = x @ (W1 a).
__global__ __launch_bounds__(256) void prep_kernel(const float* __restrict__ W1,
                                                   const float* __restrict__ as1, const float* __restrict__ ad1,
                                                   unsigned short* __restrict__ Bh, unsigned short* __restrict__ Bl) {
    int n = blockIdx.x;      // 0..271
    int k = threadIdx.x;     // 0..255
    float v;
    if (n < 256) {
        v = W1[(size_t)k * 256 + n];
    } else {
        int j = n - 256;
        int h = j & 7;
        const float* att = (j < 8) ? (as1 + h * 32) : (ad1 + h * 32);
        float s = 0.f;
        #pragma unroll
        for (int c = 0; c < 32; ++c) s += W1[(size_t)k * 256 + h * 32 + c] * att[c];
        v = s;
    }
    unsigned short hi = f2bf(v);
    Bh[n * 256 + k] = hi;
    Bl[n * 256 + k] = f2bf(v - bf2f(hi));
}

// ---------------- GEMM1 (MFMA bf16 hi/lo split, fp32-accurate) + fused alpha1 ----------------
// Block: 128 rows x 272 cols (16 h1-tiles + 1 alpha-tile). 4 waves, wave = 32 rows x all tiles.
// 3-term split: Ah*Bh + Ah*Bl + Al*Bh  (Al*Bl ~ 2^-16, dropped).
#define AKP 40   // padded k-stride in ushorts: 80 B rows -> <=2-way LDS conflicts on b128
__global__ __launch_bounds__(256, 2) void gemm1_kernel(const float* __restrict__ x,
                                                       const unsigned short* __restrict__ Bh,
                                                       const unsigned short* __restrict__ Bl,
                                                       unsigned short* __restrict__ h1b,
                                                       float* __restrict__ asrc1, float* __restrict__ adst1) {
    __shared__ __align__(16) unsigned short Ah[128 * AKP];
    __shared__ __align__(16) unsigned short Al[128 * AKP];
    __shared__ __align__(16) unsigned short Bhs[272 * AKP];
    __shared__ __align__(16) unsigned short Bls[272 * AKP];
    int tid = threadIdx.x;
    int wave = tid >> 6, lane = tid & 63;
    int quad = lane >> 4, l16 = lane & 15;
    int row0 = blockIdx.x * 128;

    float4_t acc[2][17];
    #pragma unroll
    for (int i = 0; i < 2; ++i)
        #pragma unroll
        for (int j = 0; j < 17; ++j) acc[i][j] = (float4_t){0.f, 0.f, 0.f, 0.f};

    for (int k0 = 0; k0 < 256; k0 += 32) {
        __syncthreads();
        // stage A chunk [128 x 32] fp32 -> split hi/lo bf16
        #pragma unroll
        for (int i = 0; i < 4; ++i) {
            int id = i * 256 + tid;
            int r = id >> 3, kq = id & 7;
            int rr = row0 + r; if (rr >= NN) rr = NN - 1;
            float4 v = *(const float4*)(x + (size_t)rr * 256 + k0 + kq * 4);
            ushort4 hi, lo;
            hi.x = f2bf(v.x); lo.x = f2bf(v.x - bf2f(hi.x));
            hi.y = f2bf(v.y); lo.y = f2bf(v.y - bf2f(hi.y));
            hi.z = f2bf(v.z); lo.z = f2bf(v.z - bf2f(hi.z));
            hi.w = f2bf(v.w); lo.w = f2bf(v.w - bf2f(hi.w));
            *(ushort4*)(Ah + r * AKP + kq * 4) = hi;
            *(ushort4*)(Al + r * AKP + kq * 4) = lo;
        }
        // stage B chunk [272 x 32] bf16 hi/lo (16B per id)
        for (int id = tid; id < 272 * 4; id += 256) {
            int r = id >> 2, kq = id & 3;
            *(float4*)(Bhs + r * AKP + kq * 8) = *(const float4*)(Bh + (size_t)r * 256 + k0 + kq * 8);
            *(float4*)(Bls + r * AKP + kq * 8) = *(const float4*)(Bl + (size_t)r * 256 + k0 + kq * 8);
        }
        __syncthreads();
        // A frags: A[m = lane&15][k = quad*8+j]
        short8_t ah[2], al[2];
        #pragma unroll
        for (int mt = 0; mt < 2; ++mt) {
            int mrow = wave * 32 + mt * 16 + l16;
            ah[mt] = *(const short8_t*)(Ah + mrow * AKP + quad * 8);
            al[mt] = *(const short8_t*)(Al + mrow * AKP + quad * 8);
        }
        #pragma unroll
        for (int nt = 0; nt < 17; ++nt) {
            int nrow = nt * 16 + l16;
            short8_t bh  = *(const short8_t*)(Bhs + nrow * AKP + quad * 8);
            short8_t blo = *(const short8_t*)(Bls + nrow * AKP + quad * 8);
            #pragma unroll
            for (int mt = 0; mt < 2; ++mt) {
                acc[mt][nt] = __builtin_amdgcn_mfma_f32_16x16x32_bf16(ah[mt], bh,  acc[mt][nt], 0, 0, 0);
                acc[mt][nt] = __builtin_amdgcn_mfma_f32_16x16x32_bf16(ah[mt], blo, acc[mt][nt], 0, 0, 0);
                acc[mt][nt] = __builtin_amdgcn_mfma_f32_16x16x32_bf16(al[mt], bh,  acc[mt][nt], 0, 0, 0);
            }
        }
    }
    // epilogue: C/D layout col = lane&15, row = quad*4 + reg
    #pragma unroll
    for (int mt = 0; mt < 2; ++mt) {
        int rbase = row0 + wave * 32 + mt * 16 + quad * 4;
        #pragma unroll
        for (int r = 0; r < 4; ++r) {
            int row = rbase + r;
            if (row >= NN) continue;
            #pragma unroll
            for (int nt = 0; nt < 16; ++nt)
                h1b[(size_t)row * 256 + nt * 16 + l16] = f2bf(acc[mt][nt][r]);
            float v = acc[mt][16][r];   // alpha tile: cols 0-7 = src heads, 8-15 = dst heads
            if (l16 < 8) asrc1[row * 8 + l16] = v;
            else         adst1[row * 8 + (l16 - 8)] = v;
        }
    }
}

// ---------------- layer-1 aggregation: wave per dst, bf16 gather, single-pass online softmax ----------------
__global__ __launch_bounds__(256) void agg1_kernel(const unsigned short* __restrict__ h1b, const float* __restrict__ asrc,
                                                   const float* __restrict__ adst, const int* __restrict__ esrc,
                                                   const int* __restrict__ off,
                                                   const float* __restrict__ b1, float* __restrict__ hout) {
    int wid = blockIdx.x * 4 + (threadIdx.x >> 6);
    if (wid >= NN) return;
    int lane = threadIdx.x & 63;
    int hh = lane >> 3;       // head (8 lanes per head)
    int c0 = lane * 4;        // 4 channels owned by this lane
    float adh = adst[wid * 8 + hh];
    int e0 = off[wid], e1 = off[wid + 1];
    const char* hbase = (const char*)h1b + ((size_t)c0 << 1);

    float m = -INFINITY, s = 0.f;
    float ax = 0.f, ay = 0.f, az = 0.f, aw = 0.f;

    for (int base = e0; base < e1; base += 64) {
        int cnt = e1 - base; if (cnt > 64) cnt = 64;
        int snv = esrc[base + (lane < cnt ? lane : cnt - 1)];
        int sn = __shfl(snv, 0);
        float aP = asrc[sn * 8 + hh];
        ushort4 hP = *(const ushort4*)(hbase + ((size_t)sn << 9));
        for (int j = 0; j < cnt; ++j) {
            float aC = aP; ushort4 hC = hP;
            if (j + 1 < cnt) {
                int sn2 = __shfl(snv, j + 1);
                aP = asrc[sn2 * 8 + hh];
                hP = *(const ushort4*)(hbase + ((size_t)sn2 << 9));
            }
            float e = aC + adh;
            e = (e >= 0.f) ? e : NEG * e;
            float mn = fmaxf(m, e);
            float r = __expf(m - mn);     // first iter: exp(-inf)=0
            float w = __expf(e - mn);
            s = s * r + w;
            ax = ax * r + w * bf2f(hC.x);
            ay = ay * r + w * bf2f(hC.y);
            az = az * r + w * bf2f(hC.z);
            aw = aw * r + w * bf2f(hC.w);
            m = mn;
        }
    }
    float inv = 1.f / (s + 1e-16f);
    float4 b = *(const float4*)(b1 + c0);
    float vx = ax * inv + b.x, vy = ay * inv + b.y, vz = az * inv + b.z, vw = aw * inv + b.w;
    float4 o;
    o.x = (vx > 0.f) ? vx : expm1f(vx);
    o.y = (vy > 0.f) ? vy : expm1f(vy);
    o.z = (vz > 0.f) ? vz : expm1f(vz);
    o.w = (vw > 0.f) ? vw : expm1f(vw);
    *(float4*)(hout + (size_t)wid * 256 + c0) = o;
}

// ---------------- GEMM2 (register-tiled) + fused attention logits layer 2, bf16 h2 out ----------------
#define G2_TM 128
#define G2_KC 32
__global__ __launch_bounds__(256) void gemm2_kernel(const float* __restrict__ h, const float* __restrict__ W2,
                                                    const float* __restrict__ at_s, const float* __restrict__ at_d,
                                                    unsigned short* __restrict__ h2b, float* __restrict__ as2,
                                                    float* __restrict__ ad2) {
    __shared__ __align__(16) float w2s[256 * 40];     // 40 KB
    __shared__ __align__(16) float As[G2_KC][132];    // 16.5 KB
    int tid = threadIdx.x;
    for (int i = tid; i < 256 * 40; i += 256) w2s[i] = W2[i];
    int g  = tid & 7;    // column group: cols g + 8j, j=0..4
    int rg = tid >> 3;   // row group: rows rg*4 .. rg*4+3
    int row0 = blockIdx.x * G2_TM;
    float acc[4][5] = {};
    float ats[5], atd[5];
    #pragma unroll
    for (int j = 0; j < 5; ++j) { ats[j] = at_s[g + 8 * j]; atd[j] = at_d[g + 8 * j]; }

    for (int k0 = 0; k0 < 256; k0 += G2_KC) {
        __syncthreads();
        #pragma unroll
        for (int i = 0; i < 4; ++i) {
            int id = i * 256 + tid;
            int r  = id >> 3;
            int kq = id & 7;
            int rr = row0 + r; if (rr >= NN) rr = NN - 1;
            float4 v = *(const float4*)(h + (size_t)rr * 256 + k0 + kq * 4);
            As[kq * 4 + 0][r] = v.x;
            As[kq * 4 + 1][r] = v.y;
            As[kq * 4 + 2][r] = v.z;
            As[kq * 4 + 3][r] = v.w;
        }
        __syncthreads();
        #pragma unroll 4
        for (int k = 0; k < G2_KC; ++k) {
            float4 a = *(const float4*)(&As[k][rg * 4]);
            float w[5];
            #pragma unroll
            for (int j = 0; j < 5; ++j) w[j] = w2s[(k0 + k) * 40 + g + 8 * j];
            float av[4] = {a.x, a.y, a.z, a.w};
            #pragma unroll
            for (int r = 0; r < 4; ++r)
                #pragma unroll
                for (int j = 0; j < 5; ++j)
                    acc[r][j] += av[r] * w[j];
        }
    }

    #pragma unroll
    for (int r = 0; r < 4; ++r) {
        int row = row0 + rg * 4 + r;
        float ps = 0.f, pd = 0.f;
        #pragma unroll
        for (int j = 0; j < 5; ++j) {
            ps += acc[r][j] * ats[j];
            pd += acc[r][j] * atd[j];
        }
        ps += __shfl_xor(ps, 1); pd += __shfl_xor(pd, 1);
        ps += __shfl_xor(ps, 2); pd += __shfl_xor(pd, 2);
        ps += __shfl_xor(ps, 4); pd += __shfl_xor(pd, 4);
        if (row < NN) {
            #pragma unroll
            for (int j = 0; j < 5; ++j) h2b[(size_t)row * 40 + g + 8 * j] = f2bf(acc[r][j]);
            if (g == 0) { as2[row] = ps; ad2[row] = pd; }
        }
    }
}

// ---------------- layer-2 aggregation + bias + log_softmax (bf16 gather, single-pass) ----------------
__global__ __launch_bounds__(256) void agg2_kernel(const unsigned short* __restrict__ h2b, const float* __restrict__ asrc,
                                                   const float* __restrict__ adst, const int* __restrict__ esrc,
                                                   const int* __restrict__ off,
                                                   const float* __restrict__ b2, float* __restrict__ outF,
                                                   float* __restrict__ outL) {
    int wid = blockIdx.x * 4 + (threadIdx.x >> 6);
    if (wid >= NN) return;
    int lane = threadIdx.x & 63;
    int c = lane;
    float adh = adst[wid];
    int e0 = off[wid], e1 = off[wid + 1];
    const char* hbase = (const char*)h2b + ((size_t)(c < NCLASS ? c : 0) << 1);

    float m = -INFINITY, s = 0.f, acc = 0.f;

    for (int base = e0; base < e1; base += 64) {
        int cnt = e1 - base; if (cnt > 64) cnt = 64;
        int snv = esrc[base + (lane < cnt ? lane : cnt - 1)];
        int sn = __shfl(snv, 0);
        float aP = asrc[sn];
        unsigned short hP = *(const unsigned short*)(hbase + (size_t)sn * 80);
        for (int j = 0; j < cnt; ++j) {
            float aC = aP; unsigned short hC = hP;
            if (j + 1 < cnt) {
                int sn2 = __shfl(snv, j + 1);
                aP = asrc[sn2];
                hP = *(const unsigned short*)(hbase + (size_t)sn2 * 80);
            }
            float e = aC + adh;
            e = (e >= 0.f) ? e : NEG * e;
            float mn = fmaxf(m, e);
            float r = __expf(m - mn);
            float w = __expf(e - mn);
            s = s * r + w;
            acc = acc * r + w * bf2f(hC);
            m = mn;
        }
    }
    float inv = 1.f / (s + 1e-16f);
    float fin = (c < NCLASS) ? (acc * inv + b2[c]) : -INFINITY;
    if (c < NCLASS) outF[(size_t)wid * 40 + c] = fin;
    float mx = fin;
    for (int o = 32; o; o >>= 1) mx = fmaxf(mx, __shfl_xor(mx, o));
    float ex = (c < NCLASS) ? __expf(fin - mx) : 0.f;
    float sm = ex;
    for (int o = 32; o; o >>= 1) sm += __shfl_xor(sm, o);
    if (c < NCLASS) outL[(size_t)wid * 40 + c] = fin - mx - __logf(sm);
}

extern "C" void kernel_launch(void* const* d_in, const int* in_sizes, int n_in,
                              void* d_out, int out_size, void* d_ws, size_t ws_size,
                              hipStream_t stream) {
    const float* x   = (const float*)d_in[0];
    const int*   ei  = (const int*)d_in[1];
    const float* W1  = (const float*)d_in[3];
    const float* as1 = (const float*)d_in[4];
    const float* ad1 = (const float*)d_in[5];
    const float* b1  = (const float*)d_in[6];
    const float* W2  = (const float*)d_in[7];
    const float* as2c = (const float*)d_in[8];
    const float* ad2c = (const float*)d_in[9];
    const float* b2  = (const float*)d_in[10];

    float* outF = (float*)d_out;
    float* outL = outF + (size_t)NN * NCLASS;

    char* w = (char*)d_ws;
    auto alloc = [&](size_t bytes) {
        void* p = (void*)w;
        w += (bytes + 255) & ~(size_t)255;
        return p;
    };
    unsigned short* h1b = (unsigned short*)alloc((size_t)NN * 256 * 2);
    float* hbuf  = (float*)alloc((size_t)NN * 256 * 4);
    unsigned short* h2b = (unsigned short*)alloc((size_t)NN * 40 * 2);
    float* asrc1 = (float*)alloc((size_t)NN * 8 * 4);
    float* adst1 = (float*)alloc((size_t)NN * 8 * 4);
    float* asrc2 = (float*)alloc((size_t)NN * 4);
    float* adst2 = (float*)alloc((size_t)NN * 4);
    int* deg    = (int*)alloc((size_t)NN * 4);
    int* off    = (int*)alloc((size_t)(NN + 1) * 4);
    int* cursor = (int*)alloc((size_t)NN * 4);
    int* esrc   = (int*)alloc((size_t)ET * 4);
    int* bsum   = (int*)alloc(64 * 4);
    unsigned short* W1th = (unsigned short*)alloc((size_t)272 * 256 * 2);
    unsigned short* W1tl = (unsigned short*)alloc((size_t)272 * 256 * 2);

    const int NB_SCAN = (NN + 1023) / 1024;  // 49

    hipMemsetAsync(deg, 0, (size_t)NN * 4, stream);
    hipMemsetAsync(cursor, 0, (size_t)NN * 4, stream);

    hist_kernel<<<(ET + 255) / 256, 256, 0, stream>>>(ei, deg);
    scan1_kernel<<<NB_SCAN, 256, 0, stream>>>(deg, off, bsum);
    scan2_kernel<<<1, 256, 0, stream>>>(bsum, NB_SCAN);
    scan3_kernel<<<NB_SCAN, 256, 0, stream>>>(off, bsum);
    scatter_kernel<<<(ET + 255) / 256, 256, 0, stream>>>(ei, off, cursor, esrc);

    prep_kernel<<<272, 256, 0, stream>>>(W1, as1, ad1, W1th, W1tl);
    gemm1_kernel<<<(NN + 127) / 128, 256, 0, stream>>>(x, W1th, W1tl, h1b, asrc1, adst1);
    agg1_kernel<<<(NN + 3) / 4, 256, 0, stream>>>(h1b, asrc1, adst1, esrc, off, b1, hbuf);
    gemm2_kernel<<<(NN + G2_TM - 1) / G2_TM, 256, 0, stream>>>(hbuf, W2, as2c, ad2c, h2b, asrc2, adst2);
    agg2_kernel<<<(NN + 3) / 4, 256, 0, stream>>>(h2b, asrc2, adst2, esrc, off, b2, outF, outL);
}

// Round 6
// 384.232 us; speedup vs baseline: 2.7602x; 1.0498x over previous
//
#include <hip/hip_runtime.h>
#include <hip/hip_bf16.h>
#include <math.h>

#define NN 50000
#define EE 800000
#define ET 850000   // EE + NN self loops
#define F1 256      // NHEAD*HID
#define NHEAD 8
#define HID 32
#define NCLASS 40
#define NEG 0.2f

typedef __attribute__((ext_vector_type(8))) short short8_t;   // 8 bf16 (4 VGPRs)
typedef __attribute__((ext_vector_type(4))) float float4_t;   // MFMA C/D

__device__ __forceinline__ int clampN(int v) {
    return v < 0 ? 0 : (v >= NN ? NN - 1 : v);
}
__device__ __forceinline__ unsigned short f2bf(float f) {
    __hip_bfloat16 h = __float2bfloat16(f);
    return __builtin_bit_cast(unsigned short, h);
}
__device__ __forceinline__ float bf2f(unsigned short u) {
    return __uint_as_float((unsigned)u << 16);
}

// ---------------- CSR construction ----------------
__global__ __launch_bounds__(256) void hist_kernel(const int* __restrict__ ei, int* __restrict__ deg) {
    int t = blockIdx.x * 256 + threadIdx.x;
    if (t >= ET) return;
    int d = (t < EE) ? ei[EE + t] : (t - EE);
    d = clampN(d);
    atomicAdd(&deg[d], 1);
}

__global__ __launch_bounds__(256) void scan1_kernel(const int* __restrict__ deg, int* __restrict__ off, int* __restrict__ bsum) {
    __shared__ int lds[256];
    int b = blockIdx.x, tid = threadIdx.x;
    int base = b * 1024 + tid * 4;
    int v0 = (base + 0 < NN) ? deg[base + 0] : 0;
    int v1 = (base + 1 < NN) ? deg[base + 1] : 0;
    int v2 = (base + 2 < NN) ? deg[base + 2] : 0;
    int v3 = (base + 3 < NN) ? deg[base + 3] : 0;
    int s1 = v0 + v1, s2 = s1 + v2, s3 = s2 + v3;
    lds[tid] = s3;
    __syncthreads();
    for (int o = 1; o < 256; o <<= 1) {
        int t = (tid >= o) ? lds[tid - o] : 0;
        __syncthreads();
        if (tid >= o) lds[tid] += t;
        __syncthreads();
    }
    int excl = tid ? lds[tid - 1] : 0;
    if (base + 0 < NN) off[base + 1] = excl + v0;
    if (base + 1 < NN) off[base + 2] = excl + s1;
    if (base + 2 < NN) off[base + 3] = excl + s2;
    if (base + 3 < NN) off[base + 4] = excl + s3;
    if (tid == 255) bsum[b] = lds[255];
}

__global__ __launch_bounds__(256) void scan2_kernel(int* __restrict__ bsum, int nb) {
    __shared__ int lds[256];
    int tid = threadIdx.x;
    lds[tid] = (tid < nb) ? bsum[tid] : 0;
    __syncthreads();
    for (int o = 1; o < 256; o <<= 1) {
        int t = (tid >= o) ? lds[tid - o] : 0;
        __syncthreads();
        if (tid >= o) lds[tid] += t;
        __syncthreads();
    }
    if (tid < nb) bsum[tid] = lds[tid];
}

__global__ __launch_bounds__(256) void scan3_kernel(int* __restrict__ off, const int* __restrict__ bsum) {
    int b = blockIdx.x, tid = threadIdx.x;
    if (b == 0 && tid == 0) off[0] = 0;
    if (b == 0) return;
    int add = bsum[b - 1];
    int base = b * 1024 + tid * 4;
    #pragma unroll
    for (int i = 0; i < 4; ++i) {
        if (base + i < NN) off[base + i + 1] += add;
    }
}

__global__ __launch_bounds__(256) void scatter_kernel(const int* __restrict__ ei, const int* __restrict__ off,
                                                      int* __restrict__ cursor, int* __restrict__ esrc) {
    int t = blockIdx.x * 256 + threadIdx.x;
    if (t >= ET) return;
    int s, d;
    if (t < EE) { s = ei[t]; d = ei[EE + t]; }
    else        { s = t - EE; d = t - EE; }
    s = clampN(s); d = clampN(d);
    int p = off[d] + atomicAdd(&cursor[d], 1);
    esrc[p] = s;
}

// ---------------- prep: W1t[272][256] split into bf16 hi/lo ----------------
__global__ __launch_bounds__(256) void prep_kernel(const float* __restrict__ W1,
                                                   const float* __restrict__ as1, const float* __restrict__ ad1,
                                                   unsigned short* __restrict__ Bh, unsigned short* __restrict__ Bl) {
    int n = blockIdx.x;      // 0..271
    int k = threadIdx.x;     // 0..255
    float v;
    if (n < 256) {
        v = W1[(size_t)k * 256 + n];
    } else {
        int j = n - 256;
        int h = j & 7;
        const float* att = (j < 8) ? (as1 + h * 32) : (ad1 + h * 32);
        float s = 0.f;
        #pragma unroll
        for (int c = 0; c < 32; ++c) s += W1[(size_t)k * 256 + h * 32 + c] * att[c];
        v = s;
    }
    unsigned short hi = f2bf(v);
    Bh[n * 256 + k] = hi;
    Bl[n * 256 + k] = f2bf(v - bf2f(hi));
}

// ---------------- GEMM1 (MFMA bf16 hi/lo split) + fused alpha1 ----------------
#define AKP 40
__global__ __launch_bounds__(256, 2) void gemm1_kernel(const float* __restrict__ x,
                                                       const unsigned short* __restrict__ Bh,
                                                       const unsigned short* __restrict__ Bl,
                                                       unsigned short* __restrict__ h1b,
                                                       float* __restrict__ asrc1, float* __restrict__ adst1) {
    __shared__ __align__(16) unsigned short Ah[128 * AKP];
    __shared__ __align__(16) unsigned short Al[128 * AKP];
    __shared__ __align__(16) unsigned short Bhs[272 * AKP];
    __shared__ __align__(16) unsigned short Bls[272 * AKP];
    int tid = threadIdx.x;
    int wave = tid >> 6, lane = tid & 63;
    int quad = lane >> 4, l16 = lane & 15;
    int row0 = blockIdx.x * 128;

    float4_t acc[2][17];
    #pragma unroll
    for (int i = 0; i < 2; ++i)
        #pragma unroll
        for (int j = 0; j < 17; ++j) acc[i][j] = (float4_t){0.f, 0.f, 0.f, 0.f};

    for (int k0 = 0; k0 < 256; k0 += 32) {
        __syncthreads();
        #pragma unroll
        for (int i = 0; i < 4; ++i) {
            int id = i * 256 + tid;
            int r = id >> 3, kq = id & 7;
            int rr = row0 + r; if (rr >= NN) rr = NN - 1;
            float4 v = *(const float4*)(x + (size_t)rr * 256 + k0 + kq * 4);
            ushort4 hi, lo;
            hi.x = f2bf(v.x); lo.x = f2bf(v.x - bf2f(hi.x));
            hi.y = f2bf(v.y); lo.y = f2bf(v.y - bf2f(hi.y));
            hi.z = f2bf(v.z); lo.z = f2bf(v.z - bf2f(hi.z));
            hi.w = f2bf(v.w); lo.w = f2bf(v.w - bf2f(hi.w));
            *(ushort4*)(Ah + r * AKP + kq * 4) = hi;
            *(ushort4*)(Al + r * AKP + kq * 4) = lo;
        }
        for (int id = tid; id < 272 * 4; id += 256) {
            int r = id >> 2, kq = id & 3;
            *(float4*)(Bhs + r * AKP + kq * 8) = *(const float4*)(Bh + (size_t)r * 256 + k0 + kq * 8);
            *(float4*)(Bls + r * AKP + kq * 8) = *(const float4*)(Bl + (size_t)r * 256 + k0 + kq * 8);
        }
        __syncthreads();
        short8_t ah[2], al[2];
        #pragma unroll
        for (int mt = 0; mt < 2; ++mt) {
            int mrow = wave * 32 + mt * 16 + l16;
            ah[mt] = *(const short8_t*)(Ah + mrow * AKP + quad * 8);
            al[mt] = *(const short8_t*)(Al + mrow * AKP + quad * 8);
        }
        #pragma unroll
        for (int nt = 0; nt < 17; ++nt) {
            int nrow = nt * 16 + l16;
            short8_t bh  = *(const short8_t*)(Bhs + nrow * AKP + quad * 8);
            short8_t blo = *(const short8_t*)(Bls + nrow * AKP + quad * 8);
            #pragma unroll
            for (int mt = 0; mt < 2; ++mt) {
                acc[mt][nt] = __builtin_amdgcn_mfma_f32_16x16x32_bf16(ah[mt], bh,  acc[mt][nt], 0, 0, 0);
                acc[mt][nt] = __builtin_amdgcn_mfma_f32_16x16x32_bf16(ah[mt], blo, acc[mt][nt], 0, 0, 0);
                acc[mt][nt] = __builtin_amdgcn_mfma_f32_16x16x32_bf16(al[mt], bh,  acc[mt][nt], 0, 0, 0);
            }
        }
    }
    #pragma unroll
    for (int mt = 0; mt < 2; ++mt) {
        int rbase = row0 + wave * 32 + mt * 16 + quad * 4;
        #pragma unroll
        for (int r = 0; r < 4; ++r) {
            int row = rbase + r;
            if (row >= NN) continue;
            #pragma unroll
            for (int nt = 0; nt < 16; ++nt)
                h1b[(size_t)row * 256 + nt * 16 + l16] = f2bf(acc[mt][nt][r]);
            float v = acc[mt][16][r];
            if (l16 < 8) asrc1[row * 8 + l16] = v;
            else         adst1[row * 8 + (l16 - 8)] = v;
        }
    }
}

// ---------------- layer-1 aggregation: parallel softmax weights ----------------
// Wave per dst node. Phase side: lane = jp*8+hp handles (edge-slot jp, head hp) —
// softmax chain computed once per (edge,head), not 8x redundantly.
// Channel side: lane owns channels c0=lane*4 (head hc=lane>>3); w via shfl.
__global__ __launch_bounds__(256) void agg1_kernel(const unsigned short* __restrict__ h1b, const float* __restrict__ asrc,
                                                   const float* __restrict__ adst, const int* __restrict__ esrc,
                                                   const int* __restrict__ off,
                                                   const float* __restrict__ b1, float* __restrict__ hout) {
    int wid = blockIdx.x * 4 + (threadIdx.x >> 6);
    if (wid >= NN) return;
    int lane = threadIdx.x & 63;
    int hp = lane & 7;        // phase head
    int jp = lane >> 3;       // phase edge slot (0..7)
    int hc = lane >> 3;       // channel head
    int c0 = lane * 4;        // channels owned
    float adh_p = adst[wid * 8 + hp];
    int e0 = off[wid], e1 = off[wid + 1];
    const char* hb = (const char*)h1b + ((size_t)c0 << 1);
    const char* ab = (const char*)asrc + hp * 4;

    float m = -INFINITY, s = 0.f;
    float ax = 0.f, ay = 0.f, az = 0.f, aw = 0.f;

    for (int base = e0; base < e1; base += 64) {
        int cnt = e1 - base; if (cnt > 64) cnt = 64;
        int snv = esrc[base + (lane < cnt ? lane : cnt - 1)];
        int nch = (cnt + 7) >> 3;
        for (int cj = 0; cj < nch; ++cj) {
            // ---- phase: weight for (edge cj*8+jp, head hp) ----
            int jedge = cj * 8 + jp;
            int sj = __shfl(snv, jedge);
            float a = *(const float*)(ab + (unsigned)sj * 32);
            float e = a + adh_p;
            e = (e >= 0.f) ? e : NEG * e;
            if (jedge >= cnt) e = -INFINITY;
            float cm = e;
            cm = fmaxf(cm, __shfl_xor(cm, 8));
            cm = fmaxf(cm, __shfl_xor(cm, 16));
            cm = fmaxf(cm, __shfl_xor(cm, 32));   // per-head chunk max
            float mn = fmaxf(m, cm);
            float t = __expf(m - mn);             // rescale (uniform within head)
            float w = __expf(e - mn);             // 0 for invalid (e=-inf)
            s = s * t + w;                        // per-lane partial (my jp slot)
            m = mn;
            // ---- channel: accumulate 8 edges ----
            float rrc = __shfl(t, hc);            // rescale for my channel head
            ax *= rrc; ay *= rrc; az *= rrc; aw *= rrc;
            #pragma unroll
            for (int j = 0; j < 8; ++j) {
                float wj = __shfl(w, j * 8 + hc);
                int sj2 = __shfl(snv, cj * 8 + j);
                ushort4 hv = *(const ushort4*)(hb + ((unsigned)sj2 << 9));
                ax += wj * bf2f(hv.x);
                ay += wj * bf2f(hv.y);
                az += wj * bf2f(hv.z);
                aw += wj * bf2f(hv.w);
            }
        }
    }
    // total s per phase-head: reduce over jp slots
    s += __shfl_xor(s, 8);
    s += __shfl_xor(s, 16);
    s += __shfl_xor(s, 32);
    float sh = __shfl(s, hc);   // s for my channel head
    float inv = 1.f / (sh + 1e-16f);
    float4 b = *(const float4*)(b1 + c0);
    float vx = ax * inv + b.x, vy = ay * inv + b.y, vz = az * inv + b.z, vw = aw * inv + b.w;
    float4 o;
    o.x = (vx > 0.f) ? vx : expm1f(vx);
    o.y = (vy > 0.f) ? vy : expm1f(vy);
    o.z = (vz > 0.f) ? vz : expm1f(vz);
    o.w = (vw > 0.f) ? vw : expm1f(vw);
    *(float4*)(hout + (size_t)wid * 256 + c0) = o;
}

// ---------------- GEMM2 (register-tiled) + fused attention logits layer 2, bf16 h2 out ----------------
#define G2_TM 128
#define G2_KC 32
__global__ __launch_bounds__(256) void gemm2_kernel(const float* __restrict__ h, const float* __restrict__ W2,
                                                    const float* __restrict__ at_s, const float* __restrict__ at_d,
                                                    unsigned short* __restrict__ h2b, float* __restrict__ as2,
                                                    float* __restrict__ ad2) {
    __shared__ __align__(16) float w2s[256 * 40];
    __shared__ __align__(16) float As[G2_KC][132];
    int tid = threadIdx.x;
    for (int i = tid; i < 256 * 40; i += 256) w2s[i] = W2[i];
    int g  = tid & 7;
    int rg = tid >> 3;
    int row0 = blockIdx.x * G2_TM;
    float acc[4][5] = {};
    float ats[5], atd[5];
    #pragma unroll
    for (int j = 0; j < 5; ++j) { ats[j] = at_s[g + 8 * j]; atd[j] = at_d[g + 8 * j]; }

    for (int k0 = 0; k0 < 256; k0 += G2_KC) {
        __syncthreads();
        #pragma unroll
        for (int i = 0; i < 4; ++i) {
            int id = i * 256 + tid;
            int r  = id >> 3;
            int kq = id & 7;
            int rr = row0 + r; if (rr >= NN) rr = NN - 1;
            float4 v = *(const float4*)(h + (size_t)rr * 256 + k0 + kq * 4);
            As[kq * 4 + 0][r] = v.x;
            As[kq * 4 + 1][r] = v.y;
            As[kq * 4 + 2][r] = v.z;
            As[kq * 4 + 3][r] = v.w;
        }
        __syncthreads();
        #pragma unroll 4
        for (int k = 0; k < G2_KC; ++k) {
            float4 a = *(const float4*)(&As[k][rg * 4]);
            float w[5];
            #pragma unroll
            for (int j = 0; j < 5; ++j) w[j] = w2s[(k0 + k) * 40 + g + 8 * j];
            float av[4] = {a.x, a.y, a.z, a.w};
            #pragma unroll
            for (int r = 0; r < 4; ++r)
                #pragma unroll
                for (int j = 0; j < 5; ++j)
                    acc[r][j] += av[r] * w[j];
        }
    }

    #pragma unroll
    for (int r = 0; r < 4; ++r) {
        int row = row0 + rg * 4 + r;
        float ps = 0.f, pd = 0.f;
        #pragma unroll
        for (int j = 0; j < 5; ++j) {
            ps += acc[r][j] * ats[j];
            pd += acc[r][j] * atd[j];
        }
        ps += __shfl_xor(ps, 1); pd += __shfl_xor(pd, 1);
        ps += __shfl_xor(ps, 2); pd += __shfl_xor(pd, 2);
        ps += __shfl_xor(ps, 4); pd += __shfl_xor(pd, 4);
        if (row < NN) {
            #pragma unroll
            for (int j = 0; j < 5; ++j) h2b[(size_t)row * 40 + g + 8 * j] = f2bf(acc[r][j]);
            if (g == 0) { as2[row] = ps; ad2[row] = pd; }
        }
    }
}

// ---------------- layer-2 aggregation: fully parallel weights (single head) ----------------
__global__ __launch_bounds__(256) void agg2_kernel(const unsigned short* __restrict__ h2b, const float* __restrict__ asrc,
                                                   const float* __restrict__ adst, const int* __restrict__ esrc,
                                                   const int* __restrict__ off,
                                                   const float* __restrict__ b2, float* __restrict__ outF,
                                                   float* __restrict__ outL) {
    int wid = blockIdx.x * 4 + (threadIdx.x >> 6);
    if (wid >= NN) return;
    int lane = threadIdx.x & 63;
    int c = lane;
    float adh = adst[wid];
    int e0 = off[wid], e1 = off[wid + 1];
    const char* hb = (const char*)h2b + ((unsigned)(c < NCLASS ? c : 0) << 1);

    float m = -INFINITY, s = 0.f, acc = 0.f;

    for (int base = e0; base < e1; base += 64) {
        int cnt = e1 - base; if (cnt > 64) cnt = 64;
        int snv = esrc[base + (lane < cnt ? lane : cnt - 1)];
        // phase: my edge = lane
        float a = asrc[snv];
        float e = a + adh;
        e = (e >= 0.f) ? e : NEG * e;
        if (lane >= cnt) e = -INFINITY;
        float cm = e;
        cm = fmaxf(cm, __shfl_xor(cm, 1));
        cm = fmaxf(cm, __shfl_xor(cm, 2));
        cm = fmaxf(cm, __shfl_xor(cm, 4));
        cm = fmaxf(cm, __shfl_xor(cm, 8));
        cm = fmaxf(cm, __shfl_xor(cm, 16));
        cm = fmaxf(cm, __shfl_xor(cm, 32));
        float mn = fmaxf(m, cm);
        float t = __expf(m - mn);   // uniform across wave
        float w = __expf(e - mn);
        s = s * t + w;              // per-lane partial
        m = mn;
        acc *= t;
        #pragma unroll 1
        for (int j0 = 0; j0 < 64; j0 += 16) {
            if (j0 >= cnt) break;
            #pragma unroll
            for (int j = 0; j < 16; ++j) {
                float wj = __shfl(w, j0 + j);
                int sj = __shfl(snv, j0 + j);
                unsigned short hv = *(const unsigned short*)(hb + (unsigned)sj * 80);
                acc += wj * bf2f(hv);
            }
        }
    }
    // total s: reduce over all 64 lanes
    s += __shfl_xor(s, 1);
    s += __shfl_xor(s, 2);
    s += __shfl_xor(s, 4);
    s += __shfl_xor(s, 8);
    s += __shfl_xor(s, 16);
    s += __shfl_xor(s, 32);
    float inv = 1.f / (s + 1e-16f);
    float fin = (c < NCLASS) ? (acc * inv + b2[c]) : -INFINITY;
    if (c < NCLASS) outF[(size_t)wid * 40 + c] = fin;
    float mx = fin;
    for (int o = 32; o; o >>= 1) mx = fmaxf(mx, __shfl_xor(mx, o));
    float ex = (c < NCLASS) ? __expf(fin - mx) : 0.f;
    float sm = ex;
    for (int o = 32; o; o >>= 1) sm += __shfl_xor(sm, o);
    if (c < NCLASS) outL[(size_t)wid * 40 + c] = fin - mx - __logf(sm);
}

extern "C" void kernel_launch(void* const* d_in, const int* in_sizes, int n_in,
                              void* d_out, int out_size, void* d_ws, size_t ws_size,
                              hipStream_t stream) {
    const float* x   = (const float*)d_in[0];
    const int*   ei  = (const int*)d_in[1];
    const float* W1  = (const float*)d_in[3];
    const float* as1 = (const float*)d_in[4];
    const float* ad1 = (const float*)d_in[5];
    const float* b1  = (const float*)d_in[6];
    const float* W2  = (const float*)d_in[7];
    const float* as2c = (const float*)d_in[8];
    const float* ad2c = (const float*)d_in[9];
    const float* b2  = (const float*)d_in[10];

    float* outF = (float*)d_out;
    float* outL = outF + (size_t)NN * NCLASS;

    char* w = (char*)d_ws;
    auto alloc = [&](size_t bytes) {
        void* p = (void*)w;
        w += (bytes + 255) & ~(size_t)255;
        return p;
    };
    unsigned short* h1b = (unsigned short*)alloc((size_t)NN * 256 * 2);
    float* hbuf  = (float*)alloc((size_t)NN * 256 * 4);
    unsigned short* h2b = (unsigned short*)alloc((size_t)NN * 40 * 2);
    float* asrc1 = (float*)alloc((size_t)NN * 8 * 4);
    float* adst1 = (float*)alloc((size_t)NN * 8 * 4);
    float* asrc2 = (float*)alloc((size_t)NN * 4);
    float* adst2 = (float*)alloc((size_t)NN * 4);
    int* deg    = (int*)alloc((size_t)NN * 4);
    int* off    = (int*)alloc((size_t)(NN + 1) * 4);
    int* cursor = (int*)alloc((size_t)NN * 4);
    int* esrc   = (int*)alloc((size_t)ET * 4);
    int* bsum   = (int*)alloc(64 * 4);
    unsigned short* W1th = (unsigned short*)alloc((size_t)272 * 256 * 2);
    unsigned short* W1tl = (unsigned short*)alloc((size_t)272 * 256 * 2);

    const int NB_SCAN = (NN + 1023) / 1024;  // 49

    hipMemsetAsync(deg, 0, (size_t)NN * 4, stream);
    hipMemsetAsync(cursor, 0, (size_t)NN * 4, stream);

    hist_kernel<<<(ET + 255) / 256, 256, 0, stream>>>(ei, deg);
    scan1_kernel<<<NB_SCAN, 256, 0, stream>>>(deg, off, bsum);
    scan2_kernel<<<1, 256, 0, stream>>>(bsum, NB_SCAN);
    scan3_kernel<<<NB_SCAN, 256, 0, stream>>>(off, bsum);
    scatter_kernel<<<(ET + 255) / 256, 256, 0, stream>>>(ei, off, cursor, esrc);

    prep_kernel<<<272, 256, 0, stream>>>(W1, as1, ad1, W1th, W1tl);
    gemm1_kernel<<<(NN + 127) / 128, 256, 0, stream>>>(x, W1th, W1tl, h1b, asrc1, adst1);
    agg1_kernel<<<(NN + 3) / 4, 256, 0, stream>>>(h1b, asrc1, adst1, esrc, off, b1, hbuf);
    gemm2_kernel<<<(NN + G2_TM - 1) / G2_TM, 256, 0, stream>>>(hbuf, W2, as2c, ad2c, h2b, asrc2, adst2);
    agg2_kernel<<<(NN + 3) / 4, 256, 0, stream>>>(h2b, asrc2, adst2, esrc, off, b2, outF, outL);
}

// Round 7
// 376.413 us; speedup vs baseline: 2.8175x; 1.0208x over previous
//
#include <hip/hip_runtime.h>
#include <hip/hip_bf16.h>
#include <math.h>

#define NN 50000
#define EE 800000
#define ET 850000   // EE + NN self loops
#define F1 256      // NHEAD*HID
#define NHEAD 8
#define HID 32
#define NCLASS 40
#define NEG 0.2f

typedef __attribute__((ext_vector_type(8))) short short8_t;   // 8 bf16 (4 VGPRs)
typedef __attribute__((ext_vector_type(4))) float float4_t;   // MFMA C/D

__device__ __forceinline__ int clampN(int v) {
    return v < 0 ? 0 : (v >= NN ? NN - 1 : v);
}
__device__ __forceinline__ unsigned short f2bf(float f) {
    __hip_bfloat16 h = __float2bfloat16(f);
    return __builtin_bit_cast(unsigned short, h);
}
__device__ __forceinline__ float bf2f(unsigned short u) {
    return __uint_as_float((unsigned)u << 16);
}

// ---------------- CSR construction ----------------
__global__ __launch_bounds__(256) void hist_kernel(const int* __restrict__ ei, int* __restrict__ deg) {
    int t = blockIdx.x * 256 + threadIdx.x;
    if (t >= ET) return;
    int d = (t < EE) ? ei[EE + t] : (t - EE);
    d = clampN(d);
    atomicAdd(&deg[d], 1);
}

__global__ __launch_bounds__(256) void scan1_kernel(const int* __restrict__ deg, int* __restrict__ off, int* __restrict__ bsum) {
    __shared__ int lds[256];
    int b = blockIdx.x, tid = threadIdx.x;
    int base = b * 1024 + tid * 4;
    int v0 = (base + 0 < NN) ? deg[base + 0] : 0;
    int v1 = (base + 1 < NN) ? deg[base + 1] : 0;
    int v2 = (base + 2 < NN) ? deg[base + 2] : 0;
    int v3 = (base + 3 < NN) ? deg[base + 3] : 0;
    int s1 = v0 + v1, s2 = s1 + v2, s3 = s2 + v3;
    lds[tid] = s3;
    __syncthreads();
    for (int o = 1; o < 256; o <<= 1) {
        int t = (tid >= o) ? lds[tid - o] : 0;
        __syncthreads();
        if (tid >= o) lds[tid] += t;
        __syncthreads();
    }
    int excl = tid ? lds[tid - 1] : 0;
    if (base + 0 < NN) off[base + 1] = excl + v0;
    if (base + 1 < NN) off[base + 2] = excl + s1;
    if (base + 2 < NN) off[base + 3] = excl + s2;
    if (base + 3 < NN) off[base + 4] = excl + s3;
    if (tid == 255) bsum[b] = lds[255];
}

__global__ __launch_bounds__(256) void scan2_kernel(int* __restrict__ bsum, int nb) {
    __shared__ int lds[256];
    int tid = threadIdx.x;
    lds[tid] = (tid < nb) ? bsum[tid] : 0;
    __syncthreads();
    for (int o = 1; o < 256; o <<= 1) {
        int t = (tid >= o) ? lds[tid - o] : 0;
        __syncthreads();
        if (tid >= o) lds[tid] += t;
        __syncthreads();
    }
    if (tid < nb) bsum[tid] = lds[tid];
}

__global__ __launch_bounds__(256) void scan3_kernel(int* __restrict__ off, const int* __restrict__ bsum) {
    int b = blockIdx.x, tid = threadIdx.x;
    if (b == 0 && tid == 0) off[0] = 0;
    if (b == 0) return;
    int add = bsum[b - 1];
    int base = b * 1024 + tid * 4;
    #pragma unroll
    for (int i = 0; i < 4; ++i) {
        if (base + i < NN) off[base + i + 1] += add;
    }
}

__global__ __launch_bounds__(256) void scatter_kernel(const int* __restrict__ ei, const int* __restrict__ off,
                                                      int* __restrict__ cursor, int* __restrict__ esrc) {
    int t = blockIdx.x * 256 + threadIdx.x;
    if (t >= ET) return;
    int s, d;
    if (t < EE) { s = ei[t]; d = ei[EE + t]; }
    else        { s = t - EE; d = t - EE; }
    s = clampN(s); d = clampN(d);
    int p = off[d] + atomicAdd(&cursor[d], 1);
    esrc[p] = s;
}

// ---------------- prep: W1t[272][256] split into bf16 hi/lo ----------------
__global__ __launch_bounds__(256) void prep_kernel(const float* __restrict__ W1,
                                                   const float* __restrict__ as1, const float* __restrict__ ad1,
                                                   unsigned short* __restrict__ Bh, unsigned short* __restrict__ Bl) {
    int n = blockIdx.x;      // 0..271
    int k = threadIdx.x;     // 0..255
    float v;
    if (n < 256) {
        v = W1[(size_t)k * 256 + n];
    } else {
        int j = n - 256;
        int h = j & 7;
        const float* att = (j < 8) ? (as1 + h * 32) : (ad1 + h * 32);
        float s = 0.f;
        #pragma unroll
        for (int c = 0; c < 32; ++c) s += W1[(size_t)k * 256 + h * 32 + c] * att[c];
        v = s;
    }
    unsigned short hi = f2bf(v);
    Bh[n * 256 + k] = hi;
    Bl[n * 256 + k] = f2bf(v - bf2f(hi));
}

// ---------------- GEMM1 (MFMA bf16 hi/lo split) + fused alpha1 ----------------
#define AKP 40
__global__ __launch_bounds__(256, 2) void gemm1_kernel(const float* __restrict__ x,
                                                       const unsigned short* __restrict__ Bh,
                                                       const unsigned short* __restrict__ Bl,
                                                       unsigned short* __restrict__ h1b,
                                                       float* __restrict__ asrc1, float* __restrict__ adst1) {
    __shared__ __align__(16) unsigned short Ah[128 * AKP];
    __shared__ __align__(16) unsigned short Al[128 * AKP];
    __shared__ __align__(16) unsigned short Bhs[272 * AKP];
    __shared__ __align__(16) unsigned short Bls[272 * AKP];
    int tid = threadIdx.x;
    int wave = tid >> 6, lane = tid & 63;
    int quad = lane >> 4, l16 = lane & 15;
    int row0 = blockIdx.x * 128;

    float4_t acc[2][17];
    #pragma unroll
    for (int i = 0; i < 2; ++i)
        #pragma unroll
        for (int j = 0; j < 17; ++j) acc[i][j] = (float4_t){0.f, 0.f, 0.f, 0.f};

    for (int k0 = 0; k0 < 256; k0 += 32) {
        __syncthreads();
        #pragma unroll
        for (int i = 0; i < 4; ++i) {
            int id = i * 256 + tid;
            int r = id >> 3, kq = id & 7;
            int rr = row0 + r; if (rr >= NN) rr = NN - 1;
            float4 v = *(const float4*)(x + (size_t)rr * 256 + k0 + kq * 4);
            ushort4 hi, lo;
            hi.x = f2bf(v.x); lo.x = f2bf(v.x - bf2f(hi.x));
            hi.y = f2bf(v.y); lo.y = f2bf(v.y - bf2f(hi.y));
            hi.z = f2bf(v.z); lo.z = f2bf(v.z - bf2f(hi.z));
            hi.w = f2bf(v.w); lo.w = f2bf(v.w - bf2f(hi.w));
            *(ushort4*)(Ah + r * AKP + kq * 4) = hi;
            *(ushort4*)(Al + r * AKP + kq * 4) = lo;
        }
        for (int id = tid; id < 272 * 4; id += 256) {
            int r = id >> 2, kq = id & 3;
            *(float4*)(Bhs + r * AKP + kq * 8) = *(const float4*)(Bh + (size_t)r * 256 + k0 + kq * 8);
            *(float4*)(Bls + r * AKP + kq * 8) = *(const float4*)(Bl + (size_t)r * 256 + k0 + kq * 8);
        }
        __syncthreads();
        short8_t ah[2], al[2];
        #pragma unroll
        for (int mt = 0; mt < 2; ++mt) {
            int mrow = wave * 32 + mt * 16 + l16;
            ah[mt] = *(const short8_t*)(Ah + mrow * AKP + quad * 8);
            al[mt] = *(const short8_t*)(Al + mrow * AKP + quad * 8);
        }
        #pragma unroll
        for (int nt = 0; nt < 17; ++nt) {
            int nrow = nt * 16 + l16;
            short8_t bh  = *(const short8_t*)(Bhs + nrow * AKP + quad * 8);
            short8_t blo = *(const short8_t*)(Bls + nrow * AKP + quad * 8);
            #pragma unroll
            for (int mt = 0; mt < 2; ++mt) {
                acc[mt][nt] = __builtin_amdgcn_mfma_f32_16x16x32_bf16(ah[mt], bh,  acc[mt][nt], 0, 0, 0);
                acc[mt][nt] = __builtin_amdgcn_mfma_f32_16x16x32_bf16(ah[mt], blo, acc[mt][nt], 0, 0, 0);
                acc[mt][nt] = __builtin_amdgcn_mfma_f32_16x16x32_bf16(al[mt], bh,  acc[mt][nt], 0, 0, 0);
            }
        }
    }
    #pragma unroll
    for (int mt = 0; mt < 2; ++mt) {
        int rbase = row0 + wave * 32 + mt * 16 + quad * 4;
        #pragma unroll
        for (int r = 0; r < 4; ++r) {
            int row = rbase + r;
            if (row >= NN) continue;
            #pragma unroll
            for (int nt = 0; nt < 16; ++nt)
                h1b[(size_t)row * 256 + nt * 16 + l16] = f2bf(acc[mt][nt][r]);
            float v = acc[mt][16][r];
            if (l16 < 8) asrc1[row * 8 + l16] = v;
            else         adst1[row * 8 + (l16 - 8)] = v;
        }
    }
}

// ---------------- layer-1 aggregation: LDS-staged weights, packed decode ----------------
// Wave per dst. Phase lane = (edge-slot jp, head hp) computes w once; stages (w, sn)
// into wave-private LDS; channel loop does ONE wave-uniform ds_read_b64 per edge
// (broadcast) instead of two ds_bpermute. bf16 pairs decoded with shl/and.
__global__ __launch_bounds__(256) void agg1_kernel(const unsigned short* __restrict__ h1b, const float* __restrict__ asrc,
                                                   const float* __restrict__ adst, const int* __restrict__ esrc,
                                                   const int* __restrict__ off,
                                                   const float* __restrict__ b1, float* __restrict__ hout) {
    __shared__ __align__(8) float2 pairs[4][64];   // per-wave (w, sn_bits)
    int tid = threadIdx.x;
    int wave = tid >> 6;
    int wid = blockIdx.x * 4 + wave;
    if (wid >= NN) return;
    int lane = tid & 63;
    int hp = lane & 7;        // phase head
    int jp = lane >> 3;       // phase edge slot
    int hc = lane >> 3;       // channel head
    int c0 = lane * 4;        // channels owned
    float adh_p = adst[wid * 8 + hp];
    int e0 = off[wid], e1 = off[wid + 1];
    const char* hb = (const char*)h1b + ((size_t)c0 << 1);

    float m = -INFINITY, s = 0.f;
    float ax = 0.f, ay = 0.f, az = 0.f, aw = 0.f;

    for (int base = e0; base < e1; base += 64) {
        int cnt = e1 - base; if (cnt > 64) cnt = 64;
        int snv = esrc[base + (lane < cnt ? lane : cnt - 1)];
        int nch = (cnt + 7) >> 3;
        for (int cj = 0; cj < nch; ++cj) {
            // ---- phase: weight for (edge cj*8+jp, head hp) ----
            int jedge = cj * 8 + jp;
            int sj = __shfl(snv, jedge);
            float a = asrc[sj * 8 + hp];
            float e = a + adh_p;
            e = (e >= 0.f) ? e : NEG * e;
            if (jedge >= cnt) e = -INFINITY;
            float cm = e;
            cm = fmaxf(cm, __shfl_xor(cm, 8));
            cm = fmaxf(cm, __shfl_xor(cm, 16));
            cm = fmaxf(cm, __shfl_xor(cm, 32));   // per-head chunk max
            float mn = fmaxf(m, cm);
            float t = __expf(m - mn);             // uniform within head
            float w = __expf(e - mn);             // 0 for invalid
            s = s * t + w;
            m = mn;
            pairs[wave][lane] = make_float2(w, __int_as_float(sj));
            // ---- channel: rescale + accumulate 8 edges ----
            float rrc = __shfl(t, hc);            // t of my channel head (lane hc: jp=0,hp=hc)
            ax *= rrc; ay *= rrc; az *= rrc; aw *= rrc;
            const float2* rp = &pairs[wave][hc];  // slot j*8+hc, j=0..7
            #pragma unroll
            for (int j = 0; j < 8; ++j) {
                float2 pr = rp[j * 8];
                float wj = pr.x;
                int sj2 = __float_as_int(pr.y);
                uint2 u = *(const uint2*)(hb + ((size_t)(unsigned)sj2 << 9));
                ax += wj * __uint_as_float(u.x << 16);
                ay += wj * __uint_as_float(u.x & 0xFFFF0000u);
                az += wj * __uint_as_float(u.y << 16);
                aw += wj * __uint_as_float(u.y & 0xFFFF0000u);
            }
        }
    }
    // total s per phase-head: reduce over jp slots
    s += __shfl_xor(s, 8);
    s += __shfl_xor(s, 16);
    s += __shfl_xor(s, 32);
    float sh = __shfl(s, hc);
    float inv = 1.f / (sh + 1e-16f);
    float4 b = *(const float4*)(b1 + c0);
    float vx = ax * inv + b.x, vy = ay * inv + b.y, vz = az * inv + b.z, vw = aw * inv + b.w;
    float4 o;
    o.x = (vx > 0.f) ? vx : expm1f(vx);
    o.y = (vy > 0.f) ? vy : expm1f(vy);
    o.z = (vz > 0.f) ? vz : expm1f(vz);
    o.w = (vw > 0.f) ? vw : expm1f(vw);
    *(float4*)(hout + (size_t)wid * 256 + c0) = o;
}

// ---------------- GEMM2 (register-tiled) + fused attention logits layer 2, bf16 h2 out ----------------
#define G2_TM 128
#define G2_KC 32
__global__ __launch_bounds__(256) void gemm2_kernel(const float* __restrict__ h, const float* __restrict__ W2,
                                                    const float* __restrict__ at_s, const float* __restrict__ at_d,
                                                    unsigned short* __restrict__ h2b, float* __restrict__ as2,
                                                    float* __restrict__ ad2) {
    __shared__ __align__(16) float w2s[256 * 40];
    __shared__ __align__(16) float As[G2_KC][132];
    int tid = threadIdx.x;
    for (int i = tid; i < 256 * 40; i += 256) w2s[i] = W2[i];
    int g  = tid & 7;
    int rg = tid >> 3;
    int row0 = blockIdx.x * G2_TM;
    float acc[4][5] = {};
    float ats[5], atd[5];
    #pragma unroll
    for (int j = 0; j < 5; ++j) { ats[j] = at_s[g + 8 * j]; atd[j] = at_d[g + 8 * j]; }

    for (int k0 = 0; k0 < 256; k0 += G2_KC) {
        __syncthreads();
        #pragma unroll
        for (int i = 0; i < 4; ++i) {
            int id = i * 256 + tid;
            int r  = id >> 3;
            int kq = id & 7;
            int rr = row0 + r; if (rr >= NN) rr = NN - 1;
            float4 v = *(const float4*)(h + (size_t)rr * 256 + k0 + kq * 4);
            As[kq * 4 + 0][r] = v.x;
            As[kq * 4 + 1][r] = v.y;
            As[kq * 4 + 2][r] = v.z;
            As[kq * 4 + 3][r] = v.w;
        }
        __syncthreads();
        #pragma unroll 4
        for (int k = 0; k < G2_KC; ++k) {
            float4 a = *(const float4*)(&As[k][rg * 4]);
            float w[5];
            #pragma unroll
            for (int j = 0; j < 5; ++j) w[j] = w2s[(k0 + k) * 40 + g + 8 * j];
            float av[4] = {a.x, a.y, a.z, a.w};
            #pragma unroll
            for (int r = 0; r < 4; ++r)
                #pragma unroll
                for (int j = 0; j < 5; ++j)
                    acc[r][j] += av[r] * w[j];
        }
    }

    #pragma unroll
    for (int r = 0; r < 4; ++r) {
        int row = row0 + rg * 4 + r;
        float ps = 0.f, pd = 0.f;
        #pragma unroll
        for (int j = 0; j < 5; ++j) {
            ps += acc[r][j] * ats[j];
            pd += acc[r][j] * atd[j];
        }
        ps += __shfl_xor(ps, 1); pd += __shfl_xor(pd, 1);
        ps += __shfl_xor(ps, 2); pd += __shfl_xor(pd, 2);
        ps += __shfl_xor(ps, 4); pd += __shfl_xor(pd, 4);
        if (row < NN) {
            #pragma unroll
            for (int j = 0; j < 5; ++j) h2b[(size_t)row * 40 + g + 8 * j] = f2bf(acc[r][j]);
            if (g == 0) { as2[row] = ps; ad2[row] = pd; }
        }
    }
}

// ---------------- layer-2 aggregation: LDS-staged weights (single head) ----------------
__global__ __launch_bounds__(256) void agg2_kernel(const unsigned short* __restrict__ h2b, const float* __restrict__ asrc,
                                                   const float* __restrict__ adst, const int* __restrict__ esrc,
                                                   const int* __restrict__ off,
                                                   const float* __restrict__ b2, float* __restrict__ outF,
                                                   float* __restrict__ outL) {
    __shared__ __align__(8) float2 pw2[4][64];
    int tid = threadIdx.x;
    int wave = tid >> 6;
    int wid = blockIdx.x * 4 + wave;
    if (wid >= NN) return;
    int lane = tid & 63;
    int c = lane;
    float adh = adst[wid];
    int e0 = off[wid], e1 = off[wid + 1];
    const char* hb = (const char*)h2b + ((unsigned)(c < NCLASS ? c : 0) << 1);

    float m = -INFINITY, s = 0.f, acc = 0.f;

    for (int base = e0; base < e1; base += 64) {
        int cnt = e1 - base; if (cnt > 64) cnt = 64;
        int snv = esrc[base + (lane < cnt ? lane : cnt - 1)];
        // phase: my edge = lane
        float a = asrc[snv];
        float e = a + adh;
        e = (e >= 0.f) ? e : NEG * e;
        if (lane >= cnt) e = -INFINITY;
        float cm = e;
        cm = fmaxf(cm, __shfl_xor(cm, 1));
        cm = fmaxf(cm, __shfl_xor(cm, 2));
        cm = fmaxf(cm, __shfl_xor(cm, 4));
        cm = fmaxf(cm, __shfl_xor(cm, 8));
        cm = fmaxf(cm, __shfl_xor(cm, 16));
        cm = fmaxf(cm, __shfl_xor(cm, 32));
        float mn = fmaxf(m, cm);
        float t = __expf(m - mn);   // uniform across wave
        float w = __expf(e - mn);
        s = s * t + w;              // per-lane partial
        m = mn;
        pw2[wave][lane] = make_float2(w, __int_as_float(snv));
        acc *= t;
        #pragma unroll 1
        for (int j0 = 0; j0 < 64; j0 += 16) {
            if (j0 >= cnt) break;
            #pragma unroll
            for (int j = 0; j < 16; ++j) {
                float2 pr = pw2[wave][j0 + j];       // wave-uniform -> broadcast
                float wj = pr.x;
                int sj = __float_as_int(pr.y);
                unsigned short hv = *(const unsigned short*)(hb + (unsigned)sj * 80);
                acc += wj * bf2f(hv);
            }
        }
    }
    // total s: reduce over all 64 lanes
    s += __shfl_xor(s, 1);
    s += __shfl_xor(s, 2);
    s += __shfl_xor(s, 4);
    s += __shfl_xor(s, 8);
    s += __shfl_xor(s, 16);
    s += __shfl_xor(s, 32);
    float inv = 1.f / (s + 1e-16f);
    float fin = (c < NCLASS) ? (acc * inv + b2[c]) : -INFINITY;
    if (c < NCLASS) outF[(size_t)wid * 40 + c] = fin;
    float mx = fin;
    for (int o = 32; o; o >>= 1) mx = fmaxf(mx, __shfl_xor(mx, o));
    float ex = (c < NCLASS) ? __expf(fin - mx) : 0.f;
    float sm = ex;
    for (int o = 32; o; o >>= 1) sm += __shfl_xor(sm, o);
    if (c < NCLASS) outL[(size_t)wid * 40 + c] = fin - mx - __logf(sm);
}

extern "C" void kernel_launch(void* const* d_in, const int* in_sizes, int n_in,
                              void* d_out, int out_size, void* d_ws, size_t ws_size,
                              hipStream_t stream) {
    const float* x   = (const float*)d_in[0];
    const int*   ei  = (const int*)d_in[1];
    const float* W1  = (const float*)d_in[3];
    const float* as1 = (const float*)d_in[4];
    const float* ad1 = (const float*)d_in[5];
    const float* b1  = (const float*)d_in[6];
    const float* W2  = (const float*)d_in[7];
    const float* as2c = (const float*)d_in[8];
    const float* ad2c = (const float*)d_in[9];
    const float* b2  = (const float*)d_in[10];

    float* outF = (float*)d_out;
    float* outL = outF + (size_t)NN * NCLASS;

    char* w = (char*)d_ws;
    auto alloc = [&](size_t bytes) {
        void* p = (void*)w;
        w += (bytes + 255) & ~(size_t)255;
        return p;
    };
    unsigned short* h1b = (unsigned short*)alloc((size_t)NN * 256 * 2);
    float* hbuf  = (float*)alloc((size_t)NN * 256 * 4);
    unsigned short* h2b = (unsigned short*)alloc((size_t)NN * 40 * 2);
    float* asrc1 = (float*)alloc((size_t)NN * 8 * 4);
    float* adst1 = (float*)alloc((size_t)NN * 8 * 4);
    float* asrc2 = (float*)alloc((size_t)NN * 4);
    float* adst2 = (float*)alloc((size_t)NN * 4);
    int* deg    = (int*)alloc((size_t)NN * 4);
    int* off    = (int*)alloc((size_t)(NN + 1) * 4);
    int* cursor = (int*)alloc((size_t)NN * 4);
    int* esrc   = (int*)alloc((size_t)ET * 4);
    int* bsum   = (int*)alloc(64 * 4);
    unsigned short* W1th = (unsigned short*)alloc((size_t)272 * 256 * 2);
    unsigned short* W1tl = (unsigned short*)alloc((size_t)272 * 256 * 2);

    const int NB_SCAN = (NN + 1023) / 1024;  // 49

    hipMemsetAsync(deg, 0, (size_t)NN * 4, stream);
    hipMemsetAsync(cursor, 0, (size_t)NN * 4, stream);

    hist_kernel<<<(ET + 255) / 256, 256, 0, stream>>>(ei, deg);
    scan1_kernel<<<NB_SCAN, 256, 0, stream>>>(deg, off, bsum);
    scan2_kernel<<<1, 256, 0, stream>>>(bsum, NB_SCAN);
    scan3_kernel<<<NB_SCAN, 256, 0, stream>>>(off, bsum);
    scatter_kernel<<<(ET + 255) / 256, 256, 0, stream>>>(ei, off, cursor, esrc);

    prep_kernel<<<272, 256, 0, stream>>>(W1, as1, ad1, W1th, W1tl);
    gemm1_kernel<<<(NN + 127) / 128, 256, 0, stream>>>(x, W1th, W1tl, h1b, asrc1, adst1);
    agg1_kernel<<<(NN + 3) / 4, 256, 0, stream>>>(h1b, asrc1, adst1, esrc, off, b1, hbuf);
    gemm2_kernel<<<(NN + G2_TM - 1) / G2_TM, 256, 0, stream>>>(hbuf, W2, as2c, ad2c, h2b, asrc2, adst2);
    agg2_kernel<<<(NN + 3) / 4, 256, 0, stream>>>(h2b, asrc2, adst2, esrc, off, b2, outF, outL);
}

// Round 8
// 373.927 us; speedup vs baseline: 2.8363x; 1.0066x over previous
//
#include <hip/hip_runtime.h>
#include <hip/hip_bf16.h>
#include <math.h>

#define NN 50000
#define EE 800000
#define ET 850000   // EE + NN self loops
#define F1 256      // NHEAD*HID
#define NHEAD 8
#define HID 32
#define NCLASS 40
#define NEG 0.2f

typedef __attribute__((ext_vector_type(8))) short short8_t;   // 8 bf16 (4 VGPRs)
typedef __attribute__((ext_vector_type(4))) float float4_t;   // MFMA C/D

__device__ __forceinline__ int clampN(int v) {
    return v < 0 ? 0 : (v >= NN ? NN - 1 : v);
}
__device__ __forceinline__ unsigned short f2bf(float f) {
    __hip_bfloat16 h = __float2bfloat16(f);
    return __builtin_bit_cast(unsigned short, h);
}
__device__ __forceinline__ float bf2f(unsigned short u) {
    return __uint_as_float((unsigned)u << 16);
}

// ---------------- CSR construction ----------------
__global__ __launch_bounds__(256) void hist_kernel(const int* __restrict__ ei, int* __restrict__ deg) {
    int t = blockIdx.x * 256 + threadIdx.x;
    if (t >= ET) return;
    int d = (t < EE) ? ei[EE + t] : (t - EE);
    d = clampN(d);
    atomicAdd(&deg[d], 1);
}

__global__ __launch_bounds__(256) void scan1_kernel(const int* __restrict__ deg, int* __restrict__ off, int* __restrict__ bsum) {
    __shared__ int lds[256];
    int b = blockIdx.x, tid = threadIdx.x;
    int base = b * 1024 + tid * 4;
    int v0 = (base + 0 < NN) ? deg[base + 0] : 0;
    int v1 = (base + 1 < NN) ? deg[base + 1] : 0;
    int v2 = (base + 2 < NN) ? deg[base + 2] : 0;
    int v3 = (base + 3 < NN) ? deg[base + 3] : 0;
    int s1 = v0 + v1, s2 = s1 + v2, s3 = s2 + v3;
    lds[tid] = s3;
    __syncthreads();
    for (int o = 1; o < 256; o <<= 1) {
        int t = (tid >= o) ? lds[tid - o] : 0;
        __syncthreads();
        if (tid >= o) lds[tid] += t;
        __syncthreads();
    }
    int excl = tid ? lds[tid - 1] : 0;
    if (base + 0 < NN) off[base + 1] = excl + v0;
    if (base + 1 < NN) off[base + 2] = excl + s1;
    if (base + 2 < NN) off[base + 3] = excl + s2;
    if (base + 3 < NN) off[base + 4] = excl + s3;
    if (tid == 255) bsum[b] = lds[255];
}

__global__ __launch_bounds__(256) void scan2_kernel(int* __restrict__ bsum, int nb) {
    __shared__ int lds[256];
    int tid = threadIdx.x;
    lds[tid] = (tid < nb) ? bsum[tid] : 0;
    __syncthreads();
    for (int o = 1; o < 256; o <<= 1) {
        int t = (tid >= o) ? lds[tid - o] : 0;
        __syncthreads();
        if (tid >= o) lds[tid] += t;
        __syncthreads();
    }
    if (tid < nb) bsum[tid] = lds[tid];
}

__global__ __launch_bounds__(256) void scan3_kernel(int* __restrict__ off, const int* __restrict__ bsum) {
    int b = blockIdx.x, tid = threadIdx.x;
    if (b == 0 && tid == 0) off[0] = 0;
    if (b == 0) return;
    int add = bsum[b - 1];
    int base = b * 1024 + tid * 4;
    #pragma unroll
    for (int i = 0; i < 4; ++i) {
        if (base + i < NN) off[base + i + 1] += add;
    }
}

__global__ __launch_bounds__(256) void scatter_kernel(const int* __restrict__ ei, const int* __restrict__ off,
                                                      int* __restrict__ cursor, int* __restrict__ esrc) {
    int t = blockIdx.x * 256 + threadIdx.x;
    if (t >= ET) return;
    int s, d;
    if (t < EE) { s = ei[t]; d = ei[EE + t]; }
    else        { s = t - EE; d = t - EE; }
    s = clampN(s); d = clampN(d);
    int p = off[d] + atomicAdd(&cursor[d], 1);
    esrc[p] = s;
}

// ---------------- prep: W1t[272][256] split into bf16 hi/lo ----------------
__global__ __launch_bounds__(256) void prep_kernel(const float* __restrict__ W1,
                                                   const float* __restrict__ as1, const float* __restrict__ ad1,
                                                   unsigned short* __restrict__ Bh, unsigned short* __restrict__ Bl) {
    int n = blockIdx.x;      // 0..271
    int k = threadIdx.x;     // 0..255
    float v;
    if (n < 256) {
        v = W1[(size_t)k * 256 + n];
    } else {
        int j = n - 256;
        int h = j & 7;
        const float* att = (j < 8) ? (as1 + h * 32) : (ad1 + h * 32);
        float s = 0.f;
        #pragma unroll
        for (int c = 0; c < 32; ++c) s += W1[(size_t)k * 256 + h * 32 + c] * att[c];
        v = s;
    }
    unsigned short hi = f2bf(v);
    Bh[n * 256 + k] = hi;
    Bl[n * 256 + k] = f2bf(v - bf2f(hi));
}

// ---------------- GEMM1 (MFMA bf16 hi/lo split) + fused alpha1 ----------------
#define AKP 40
__global__ __launch_bounds__(256, 2) void gemm1_kernel(const float* __restrict__ x,
                                                       const unsigned short* __restrict__ Bh,
                                                       const unsigned short* __restrict__ Bl,
                                                       unsigned short* __restrict__ h1b,
                                                       float* __restrict__ asrc1, float* __restrict__ adst1) {
    __shared__ __align__(16) unsigned short Ah[128 * AKP];
    __shared__ __align__(16) unsigned short Al[128 * AKP];
    __shared__ __align__(16) unsigned short Bhs[272 * AKP];
    __shared__ __align__(16) unsigned short Bls[272 * AKP];
    int tid = threadIdx.x;
    int wave = tid >> 6, lane = tid & 63;
    int quad = lane >> 4, l16 = lane & 15;
    int row0 = blockIdx.x * 128;

    float4_t acc[2][17];
    #pragma unroll
    for (int i = 0; i < 2; ++i)
        #pragma unroll
        for (int j = 0; j < 17; ++j) acc[i][j] = (float4_t){0.f, 0.f, 0.f, 0.f};

    for (int k0 = 0; k0 < 256; k0 += 32) {
        __syncthreads();
        #pragma unroll
        for (int i = 0; i < 4; ++i) {
            int id = i * 256 + tid;
            int r = id >> 3, kq = id & 7;
            int rr = row0 + r; if (rr >= NN) rr = NN - 1;
            float4 v = *(const float4*)(x + (size_t)rr * 256 + k0 + kq * 4);
            ushort4 hi, lo;
            hi.x = f2bf(v.x); lo.x = f2bf(v.x - bf2f(hi.x));
            hi.y = f2bf(v.y); lo.y = f2bf(v.y - bf2f(hi.y));
            hi.z = f2bf(v.z); lo.z = f2bf(v.z - bf2f(hi.z));
            hi.w = f2bf(v.w); lo.w = f2bf(v.w - bf2f(hi.w));
            *(ushort4*)(Ah + r * AKP + kq * 4) = hi;
            *(ushort4*)(Al + r * AKP + kq * 4) = lo;
        }
        for (int id = tid; id < 272 * 4; id += 256) {
            int r = id >> 2, kq = id & 3;
            *(float4*)(Bhs + r * AKP + kq * 8) = *(const float4*)(Bh + (size_t)r * 256 + k0 + kq * 8);
            *(float4*)(Bls + r * AKP + kq * 8) = *(const float4*)(Bl + (size_t)r * 256 + k0 + kq * 8);
        }
        __syncthreads();
        short8_t ah[2], al[2];
        #pragma unroll
        for (int mt = 0; mt < 2; ++mt) {
            int mrow = wave * 32 + mt * 16 + l16;
            ah[mt] = *(const short8_t*)(Ah + mrow * AKP + quad * 8);
            al[mt] = *(const short8_t*)(Al + mrow * AKP + quad * 8);
        }
        #pragma unroll
        for (int nt = 0; nt < 17; ++nt) {
            int nrow = nt * 16 + l16;
            short8_t bh  = *(const short8_t*)(Bhs + nrow * AKP + quad * 8);
            short8_t blo = *(const short8_t*)(Bls + nrow * AKP + quad * 8);
            #pragma unroll
            for (int mt = 0; mt < 2; ++mt) {
                acc[mt][nt] = __builtin_amdgcn_mfma_f32_16x16x32_bf16(ah[mt], bh,  acc[mt][nt], 0, 0, 0);
                acc[mt][nt] = __builtin_amdgcn_mfma_f32_16x16x32_bf16(ah[mt], blo, acc[mt][nt], 0, 0, 0);
                acc[mt][nt] = __builtin_amdgcn_mfma_f32_16x16x32_bf16(al[mt], bh,  acc[mt][nt], 0, 0, 0);
            }
        }
    }
    #pragma unroll
    for (int mt = 0; mt < 2; ++mt) {
        int rbase = row0 + wave * 32 + mt * 16 + quad * 4;
        #pragma unroll
        for (int r = 0; r < 4; ++r) {
            int row = rbase + r;
            if (row >= NN) continue;
            #pragma unroll
            for (int nt = 0; nt < 16; ++nt)
                h1b[(size_t)row * 256 + nt * 16 + l16] = f2bf(acc[mt][nt][r]);
            float v = acc[mt][16][r];
            if (l16 < 8) asrc1[row * 8 + l16] = v;
            else         adst1[row * 8 + (l16 - 8)] = v;
        }
    }
}

// ---------------- layer-1 aggregation: 3-pass per 64-edge window ----------------
// Pass A: logits for whole window into regs (no exp/shfl per chunk).
// Pass B: one max-reduce, weights -> LDS (stride-68 head rows: conflict-free b128).
// Pass C: pure gather, unroll-4, independent loads pipelined.
#define WST 68
__global__ __launch_bounds__(256) void agg1_kernel(const unsigned short* __restrict__ h1b, const float* __restrict__ asrc,
                                                   const float* __restrict__ adst, const int* __restrict__ esrc,
                                                   const int* __restrict__ off,
                                                   const float* __restrict__ b1, unsigned short* __restrict__ hout) {
    __shared__ __align__(16) float wl[4][8 * WST];
    __shared__ __align__(16) int  snl[4][64];
    int tid = threadIdx.x;
    int wave = tid >> 6;
    int wid = blockIdx.x * 4 + wave;
    if (wid >= NN) return;
    int lane = tid & 63;
    int hp = lane & 7;        // phase head
    int jp = lane >> 3;       // phase edge slot
    int hc = lane >> 3;       // channel head
    int c0 = lane * 4;        // channels owned
    float adh_p = adst[wid * 8 + hp];
    int e0 = off[wid], e1 = off[wid + 1];
    float* wlw = wl[wave];
    int* snw = snl[wave];
    const char* hb = (const char*)h1b;
    unsigned lofs = (unsigned)c0 * 2;   // lane byte offset within a row

    float m = -INFINITY, s = 0.f;
    float ax = 0.f, ay = 0.f, az = 0.f, aw = 0.f;

    for (int base = e0; base < e1; base += 64) {
        int cnt = e1 - base; if (cnt > 64) cnt = 64;
        int snv = esrc[base + (lane < cnt ? lane : cnt - 1)];
        snw[lane] = snv;
        int nch = (cnt + 7) >> 3;
        // ---- pass A: logits into regs, window max ----
        float ee[8];
        float wmax = -INFINITY;
        #pragma unroll
        for (int cj = 0; cj < 8; ++cj) {
            if (cj >= nch) { ee[cj] = -INFINITY; continue; }
            int jedge = cj * 8 + jp;
            int sj = __shfl(snv, jedge);
            float a = asrc[sj * 8 + hp];
            float e = a + adh_p;
            e = (e >= 0.f) ? e : NEG * e;
            if (jedge >= cnt) e = -INFINITY;
            ee[cj] = e;
            wmax = fmaxf(wmax, e);
        }
        wmax = fmaxf(wmax, __shfl_xor(wmax, 8));
        wmax = fmaxf(wmax, __shfl_xor(wmax, 16));
        wmax = fmaxf(wmax, __shfl_xor(wmax, 32));   // per-head window max
        float mn = fmaxf(m, wmax);
        float t = __expf(m - mn);                   // uniform within head
        m = mn;
        s *= t;
        // rescale channel accumulators once per window
        float tc = __shfl(t, hc);
        ax *= tc; ay *= tc; az *= tc; aw *= tc;
        // ---- pass B: weights -> LDS ----
        #pragma unroll
        for (int cj = 0; cj < 8; ++cj) {
            if (cj >= nch) break;
            float w = __expf(ee[cj] - mn);
            s += w;
            wlw[hp * WST + cj * 8 + jp] = w;
        }
        // ---- pass C: pure gather, 4 edges per iteration ----
        const float* wrow = wlw + hc * WST;
        for (int j = 0; j < cnt; j += 4) {
            float4 w4 = *(const float4*)(wrow + j);
            int4 sn4 = *(const int4*)(snw + j);
            uint2 u0 = *(const uint2*)(hb + (((unsigned)sn4.x << 9) + lofs));
            uint2 u1 = *(const uint2*)(hb + (((unsigned)sn4.y << 9) + lofs));
            uint2 u2 = *(const uint2*)(hb + (((unsigned)sn4.z << 9) + lofs));
            uint2 u3 = *(const uint2*)(hb + (((unsigned)sn4.w << 9) + lofs));
            ax += w4.x * __uint_as_float(u0.x << 16);
            ay += w4.x * __uint_as_float(u0.x & 0xFFFF0000u);
            az += w4.x * __uint_as_float(u0.y << 16);
            aw += w4.x * __uint_as_float(u0.y & 0xFFFF0000u);
            ax += w4.y * __uint_as_float(u1.x << 16);
            ay += w4.y * __uint_as_float(u1.x & 0xFFFF0000u);
            az += w4.y * __uint_as_float(u1.y << 16);
            aw += w4.y * __uint_as_float(u1.y & 0xFFFF0000u);
            ax += w4.z * __uint_as_float(u2.x << 16);
            ay += w4.z * __uint_as_float(u2.x & 0xFFFF0000u);
            az += w4.z * __uint_as_float(u2.y << 16);
            aw += w4.z * __uint_as_float(u2.y & 0xFFFF0000u);
            ax += w4.w * __uint_as_float(u3.x << 16);
            ay += w4.w * __uint_as_float(u3.x & 0xFFFF0000u);
            az += w4.w * __uint_as_float(u3.y << 16);
            aw += w4.w * __uint_as_float(u3.y & 0xFFFF0000u);
        }
    }
    // total s per phase-head: reduce over jp slots
    s += __shfl_xor(s, 8);
    s += __shfl_xor(s, 16);
    s += __shfl_xor(s, 32);
    float sh = __shfl(s, hc);
    float inv = 1.f / (sh + 1e-16f);
    float4 b = *(const float4*)(b1 + c0);
    float vx = ax * inv + b.x, vy = ay * inv + b.y, vz = az * inv + b.z, vw = aw * inv + b.w;
    ushort4 o;
    o.x = f2bf((vx > 0.f) ? vx : expm1f(vx));
    o.y = f2bf((vy > 0.f) ? vy : expm1f(vy));
    o.z = f2bf((vz > 0.f) ? vz : expm1f(vz));
    o.w = f2bf((vw > 0.f) ? vw : expm1f(vw));
    *(ushort4*)(hout + (size_t)wid * 256 + c0) = o;
}

// ---------------- GEMM2 (register-tiled, bf16 input) + fused alpha2, bf16 h2 out ----------------
#define G2_TM 128
#define G2_KC 32
__global__ __launch_bounds__(256) void gemm2_kernel(const unsigned short* __restrict__ h, const float* __restrict__ W2,
                                                    const float* __restrict__ at_s, const float* __restrict__ at_d,
                                                    unsigned short* __restrict__ h2b, float* __restrict__ as2,
                                                    float* __restrict__ ad2) {
    __shared__ __align__(16) float w2s[256 * 40];
    __shared__ __align__(16) float As[G2_KC][132];
    int tid = threadIdx.x;
    for (int i = tid; i < 256 * 40; i += 256) w2s[i] = W2[i];
    int g  = tid & 7;
    int rg = tid >> 3;
    int row0 = blockIdx.x * G2_TM;
    float acc[4][5] = {};
    float ats[5], atd[5];
    #pragma unroll
    for (int j = 0; j < 5; ++j) { ats[j] = at_s[g + 8 * j]; atd[j] = at_d[g + 8 * j]; }

    for (int k0 = 0; k0 < 256; k0 += G2_KC) {
        __syncthreads();
        #pragma unroll
        for (int i = 0; i < 2; ++i) {
            int id = i * 256 + tid;       // 0..511
            int r  = id >> 2;             // 0..127
            int kq = id & 3;              // 8-ushort group
            int rr = row0 + r; if (rr >= NN) rr = NN - 1;
            uint4 u = *(const uint4*)(h + (size_t)rr * 256 + k0 + kq * 8);
            As[kq * 8 + 0][r] = __uint_as_float(u.x << 16);
            As[kq * 8 + 1][r] = __uint_as_float(u.x & 0xFFFF0000u);
            As[kq * 8 + 2][r] = __uint_as_float(u.y << 16);
            As[kq * 8 + 3][r] = __uint_as_float(u.y & 0xFFFF0000u);
            As[kq * 8 + 4][r] = __uint_as_float(u.z << 16);
            As[kq * 8 + 5][r] = __uint_as_float(u.z & 0xFFFF0000u);
            As[kq * 8 + 6][r] = __uint_as_float(u.w << 16);
            As[kq * 8 + 7][r] = __uint_as_float(u.w & 0xFFFF0000u);
        }
        __syncthreads();
        #pragma unroll 4
        for (int k = 0; k < G2_KC; ++k) {
            float4 a = *(const float4*)(&As[k][rg * 4]);
            float w[5];
            #pragma unroll
            for (int j = 0; j < 5; ++j) w[j] = w2s[(k0 + k) * 40 + g + 8 * j];
            float av[4] = {a.x, a.y, a.z, a.w};
            #pragma unroll
            for (int r = 0; r < 4; ++r)
                #pragma unroll
                for (int j = 0; j < 5; ++j)
                    acc[r][j] += av[r] * w[j];
        }
    }

    #pragma unroll
    for (int r = 0; r < 4; ++r) {
        int row = row0 + rg * 4 + r;
        float ps = 0.f, pd = 0.f;
        #pragma unroll
        for (int j = 0; j < 5; ++j) {
            ps += acc[r][j] * ats[j];
            pd += acc[r][j] * atd[j];
        }
        ps += __shfl_xor(ps, 1); pd += __shfl_xor(pd, 1);
        ps += __shfl_xor(ps, 2); pd += __shfl_xor(pd, 2);
        ps += __shfl_xor(ps, 4); pd += __shfl_xor(pd, 4);
        if (row < NN) {
            #pragma unroll
            for (int j = 0; j < 5; ++j) h2b[(size_t)row * 40 + g + 8 * j] = f2bf(acc[r][j]);
            if (g == 0) { as2[row] = ps; ad2[row] = pd; }
        }
    }
}

// ---------------- layer-2 aggregation: pass-separated, unroll-4 gather ----------------
__global__ __launch_bounds__(256) void agg2_kernel(const unsigned short* __restrict__ h2b, const float* __restrict__ asrc,
                                                   const float* __restrict__ adst, const int* __restrict__ esrc,
                                                   const int* __restrict__ off,
                                                   const float* __restrict__ b2, float* __restrict__ outF,
                                                   float* __restrict__ outL) {
    __shared__ __align__(16) float wl2[4][64];
    __shared__ __align__(16) int  snl2[4][64];
    int tid = threadIdx.x;
    int wave = tid >> 6;
    int wid = blockIdx.x * 4 + wave;
    if (wid >= NN) return;
    int lane = tid & 63;
    int c = lane;
    float adh = adst[wid];
    int e0 = off[wid], e1 = off[wid + 1];
    const char* hb = (const char*)h2b + ((unsigned)(c < NCLASS ? c : 0) << 1);
    float* wlw = wl2[wave];
    int* snw = snl2[wave];

    float m = -INFINITY, s = 0.f, acc = 0.f;

    for (int base = e0; base < e1; base += 64) {
        int cnt = e1 - base; if (cnt > 64) cnt = 64;
        int snv = esrc[base + (lane < cnt ? lane : cnt - 1)];
        snw[lane] = snv;
        // phase: my edge = lane
        float a = asrc[snv];
        float e = a + adh;
        e = (e >= 0.f) ? e : NEG * e;
        if (lane >= cnt) e = -INFINITY;
        float cm = e;
        cm = fmaxf(cm, __shfl_xor(cm, 1));
        cm = fmaxf(cm, __shfl_xor(cm, 2));
        cm = fmaxf(cm, __shfl_xor(cm, 4));
        cm = fmaxf(cm, __shfl_xor(cm, 8));
        cm = fmaxf(cm, __shfl_xor(cm, 16));
        cm = fmaxf(cm, __shfl_xor(cm, 32));
        float mn = fmaxf(m, cm);
        float t = __expf(m - mn);   // uniform across wave
        float w = __expf(e - mn);
        s = s * t + w;              // per-lane partial
        m = mn;
        wlw[lane] = w;
        acc *= t;
        for (int j = 0; j < cnt; j += 4) {
            float4 w4 = *(const float4*)(wlw + j);    // broadcast
            int4 sn4 = *(const int4*)(snw + j);
            unsigned short v0 = *(const unsigned short*)(hb + (unsigned)sn4.x * 80);
            unsigned short v1 = *(const unsigned short*)(hb + (unsigned)sn4.y * 80);
            unsigned short v2 = *(const unsigned short*)(hb + (unsigned)sn4.z * 80);
            unsigned short v3 = *(const unsigned short*)(hb + (unsigned)sn4.w * 80);
            acc += w4.x * bf2f(v0);
            acc += w4.y * bf2f(v1);
            acc += w4.z * bf2f(v2);
            acc += w4.w * bf2f(v3);
        }
    }
    // total s: reduce over all 64 lanes
    s += __shfl_xor(s, 1);
    s += __shfl_xor(s, 2);
    s += __shfl_xor(s, 4);
    s += __shfl_xor(s, 8);
    s += __shfl_xor(s, 16);
    s += __shfl_xor(s, 32);
    float inv = 1.f / (s + 1e-16f);
    float fin = (c < NCLASS) ? (acc * inv + b2[c]) : -INFINITY;
    if (c < NCLASS) outF[(size_t)wid * 40 + c] = fin;
    float mx = fin;
    for (int o = 32; o; o >>= 1) mx = fmaxf(mx, __shfl_xor(mx, o));
    float ex = (c < NCLASS) ? __expf(fin - mx) : 0.f;
    float sm = ex;
    for (int o = 32; o; o >>= 1) sm += __shfl_xor(sm, o);
    if (c < NCLASS) outL[(size_t)wid * 40 + c] = fin - mx - __logf(sm);
}

extern "C" void kernel_launch(void* const* d_in, const int* in_sizes, int n_in,
                              void* d_out, int out_size, void* d_ws, size_t ws_size,
                              hipStream_t stream) {
    const float* x   = (const float*)d_in[0];
    const int*   ei  = (const int*)d_in[1];
    const float* W1  = (const float*)d_in[3];
    const float* as1 = (const float*)d_in[4];
    const float* ad1 = (const float*)d_in[5];
    const float* b1  = (const float*)d_in[6];
    const float* W2  = (const float*)d_in[7];
    const float* as2c = (const float*)d_in[8];
    const float* ad2c = (const float*)d_in[9];
    const float* b2  = (const float*)d_in[10];

    float* outF = (float*)d_out;
    float* outL = outF + (size_t)NN * NCLASS;

    char* w = (char*)d_ws;
    auto alloc = [&](size_t bytes) {
        void* p = (void*)w;
        w += (bytes + 255) & ~(size_t)255;
        return p;
    };
    unsigned short* h1b = (unsigned short*)alloc((size_t)NN * 256 * 2);
    unsigned short* hbuf = (unsigned short*)alloc((size_t)NN * 256 * 2);
    unsigned short* h2b = (unsigned short*)alloc((size_t)NN * 40 * 2);
    float* asrc1 = (float*)alloc((size_t)NN * 8 * 4);
    float* adst1 = (float*)alloc((size_t)NN * 8 * 4);
    float* asrc2 = (float*)alloc((size_t)NN * 4);
    float* adst2 = (float*)alloc((size_t)NN * 4);
    int* deg    = (int*)alloc((size_t)NN * 4);
    int* off    = (int*)alloc((size_t)(NN + 1) * 4);
    int* cursor = (int*)alloc((size_t)NN * 4);
    int* esrc   = (int*)alloc((size_t)ET * 4);
    int* bsum   = (int*)alloc(64 * 4);
    unsigned short* W1th = (unsigned short*)alloc((size_t)272 * 256 * 2);
    unsigned short* W1tl = (unsigned short*)alloc((size_t)272 * 256 * 2);

    const int NB_SCAN = (NN + 1023) / 1024;  // 49

    hipMemsetAsync(deg, 0, (size_t)NN * 4, stream);
    hipMemsetAsync(cursor, 0, (size_t)NN * 4, stream);

    hist_kernel<<<(ET + 255) / 256, 256, 0, stream>>>(ei, deg);
    scan1_kernel<<<NB_SCAN, 256, 0, stream>>>(deg, off, bsum);
    scan2_kernel<<<1, 256, 0, stream>>>(bsum, NB_SCAN);
    scan3_kernel<<<NB_SCAN, 256, 0, stream>>>(off, bsum);
    scatter_kernel<<<(ET + 255) / 256, 256, 0, stream>>>(ei, off, cursor, esrc);

    prep_kernel<<<272, 256, 0, stream>>>(W1, as1, ad1, W1th, W1tl);
    gemm1_kernel<<<(NN + 127) / 128, 256, 0, stream>>>(x, W1th, W1tl, h1b, asrc1, adst1);
    agg1_kernel<<<(NN + 3) / 4, 256, 0, stream>>>(h1b, asrc1, adst1, esrc, off, b1, hbuf);
    gemm2_kernel<<<(NN + G2_TM - 1) / G2_TM, 256, 0, stream>>>(hbuf, W2, as2c, ad2c, h2b, asrc2, adst2);
    agg2_kernel<<<(NN + 3) / 4, 256, 0, stream>>>(h2b, asrc2, adst2, esrc, off, b2, outF, outL);
}

// Round 9
// 339.125 us; speedup vs baseline: 3.1273x; 1.1026x over previous
//
#include <hip/hip_runtime.h>
#include <hip/hip_bf16.h>
#include <hip/hip_fp16.h>
#include <math.h>

#define NN 50000
#define EE 800000
#define ET 850000   // EE + NN self loops
#define F1 256      // NHEAD*HID
#define NHEAD 8
#define HID 32
#define NCLASS 40
#define NEG 0.2f

typedef __attribute__((ext_vector_type(8))) short short8_t;   // 8 bf16 (4 VGPRs)
typedef __attribute__((ext_vector_type(4))) float float4_t;   // MFMA C/D

__device__ __forceinline__ int clampN(int v) {
    return v < 0 ? 0 : (v >= NN ? NN - 1 : v);
}
__device__ __forceinline__ unsigned short f2bf(float f) {
    __hip_bfloat16 h = __float2bfloat16(f);
    return __builtin_bit_cast(unsigned short, h);
}
__device__ __forceinline__ float bf2f(unsigned short u) {
    return __uint_as_float((unsigned)u << 16);
}
__device__ __forceinline__ unsigned short f2h(float f) {
    __half h = __float2half(f);
    return __builtin_bit_cast(unsigned short, h);
}
__device__ __forceinline__ float h2f(unsigned short u) {
    __half h = __builtin_bit_cast(__half, u);
    return __half2float(h);
}
__device__ __forceinline__ float hlo2f(unsigned int u) {
    return h2f((unsigned short)(u & 0xFFFFu));
}
__device__ __forceinline__ float hhi2f(unsigned int u) {
    return h2f((unsigned short)(u >> 16));
}

// ---------------- CSR construction ----------------
// hist also assigns each edge its within-bucket rank (packed d<<15|rank) so
// scatter needs NO second atomic round.
__global__ __launch_bounds__(256) void hist_kernel(const int* __restrict__ ei, int* __restrict__ deg,
                                                   unsigned int* __restrict__ pack) {
    int t = blockIdx.x * 256 + threadIdx.x;
    if (t >= ET) return;
    int d = (t < EE) ? ei[EE + t] : (t - EE);
    d = clampN(d);
    int r = atomicAdd(&deg[d], 1);
    pack[t] = ((unsigned)d << 15) | (unsigned)r;
}

__global__ __launch_bounds__(256) void scan1_kernel(const int* __restrict__ deg, int* __restrict__ off, int* __restrict__ bsum) {
    __shared__ int lds[256];
    int b = blockIdx.x, tid = threadIdx.x;
    int base = b * 1024 + tid * 4;
    int v0 = (base + 0 < NN) ? deg[base + 0] : 0;
    int v1 = (base + 1 < NN) ? deg[base + 1] : 0;
    int v2 = (base + 2 < NN) ? deg[base + 2] : 0;
    int v3 = (base + 3 < NN) ? deg[base + 3] : 0;
    int s1 = v0 + v1, s2 = s1 + v2, s3 = s2 + v3;
    lds[tid] = s3;
    __syncthreads();
    for (int o = 1; o < 256; o <<= 1) {
        int t = (tid >= o) ? lds[tid - o] : 0;
        __syncthreads();
        if (tid >= o) lds[tid] += t;
        __syncthreads();
    }
    int excl = tid ? lds[tid - 1] : 0;
    if (base + 0 < NN) off[base + 1] = excl + v0;
    if (base + 1 < NN) off[base + 2] = excl + s1;
    if (base + 2 < NN) off[base + 3] = excl + s2;
    if (base + 3 < NN) off[base + 4] = excl + s3;
    if (tid == 255) bsum[b] = lds[255];
}

__global__ __launch_bounds__(256) void scan2_kernel(int* __restrict__ bsum, int nb) {
    __shared__ int lds[256];
    int tid = threadIdx.x;
    lds[tid] = (tid < nb) ? bsum[tid] : 0;
    __syncthreads();
    for (int o = 1; o < 256; o <<= 1) {
        int t = (tid >= o) ? lds[tid - o] : 0;
        __syncthreads();
        if (tid >= o) lds[tid] += t;
        __syncthreads();
    }
    if (tid < nb) bsum[tid] = lds[tid];
}

__global__ __launch_bounds__(256) void scan3_kernel(int* __restrict__ off, const int* __restrict__ bsum) {
    int b = blockIdx.x, tid = threadIdx.x;
    if (b == 0 && tid == 0) off[0] = 0;
    if (b == 0) return;
    int add = bsum[b - 1];
    int base = b * 1024 + tid * 4;
    #pragma unroll
    for (int i = 0; i < 4; ++i) {
        if (base + i < NN) off[base + i + 1] += add;
    }
}

// scatter: atomic-free — rank came from hist
__global__ __launch_bounds__(256) void scatter_kernel(const int* __restrict__ ei, const int* __restrict__ off,
                                                      const unsigned int* __restrict__ pack, int* __restrict__ esrc) {
    int t = blockIdx.x * 256 + threadIdx.x;
    if (t >= ET) return;
    unsigned p = pack[t];
    int d = p >> 15;
    int r = p & 0x7FFF;
    int s = (t < EE) ? ei[t] : (t - EE);
    s = clampN(s);
    esrc[off[d] + r] = s;
}

// ---------------- prep: W1t[272][256] split into bf16 hi/lo ----------------
__global__ __launch_bounds__(256) void prep_kernel(const float* __restrict__ W1,
                                                   const float* __restrict__ as1, const float* __restrict__ ad1,
                                                   unsigned short* __restrict__ Bh, unsigned short* __restrict__ Bl) {
    int n = blockIdx.x;      // 0..271
    int k = threadIdx.x;     // 0..255
    float v;
    if (n < 256) {
        v = W1[(size_t)k * 256 + n];
    } else {
        int j = n - 256;
        int h = j & 7;
        const float* att = (j < 8) ? (as1 + h * 32) : (ad1 + h * 32);
        float s = 0.f;
        #pragma unroll
        for (int c = 0; c < 32; ++c) s += W1[(size_t)k * 256 + h * 32 + c] * att[c];
        v = s;
    }
    unsigned short hi = f2bf(v);
    Bh[n * 256 + k] = hi;
    Bl[n * 256 + k] = f2bf(v - bf2f(hi));
}

// ---------------- GEMM1 (MFMA bf16 hi/lo split) + fused alpha1, fp16 h1 out ----------------
#define AKP 40
__global__ __launch_bounds__(256, 2) void gemm1_kernel(const float* __restrict__ x,
                                                       const unsigned short* __restrict__ Bh,
                                                       const unsigned short* __restrict__ Bl,
                                                       unsigned short* __restrict__ h1b,
                                                       float* __restrict__ asrc1, float* __restrict__ adst1) {
    __shared__ __align__(16) unsigned short Ah[128 * AKP];
    __shared__ __align__(16) unsigned short Al[128 * AKP];
    __shared__ __align__(16) unsigned short Bhs[272 * AKP];
    __shared__ __align__(16) unsigned short Bls[272 * AKP];
    int tid = threadIdx.x;
    int wave = tid >> 6, lane = tid & 63;
    int quad = lane >> 4, l16 = lane & 15;
    int row0 = blockIdx.x * 128;

    float4_t acc[2][17];
    #pragma unroll
    for (int i = 0; i < 2; ++i)
        #pragma unroll
        for (int j = 0; j < 17; ++j) acc[i][j] = (float4_t){0.f, 0.f, 0.f, 0.f};

    for (int k0 = 0; k0 < 256; k0 += 32) {
        __syncthreads();
        #pragma unroll
        for (int i = 0; i < 4; ++i) {
            int id = i * 256 + tid;
            int r = id >> 3, kq = id & 7;
            int rr = row0 + r; if (rr >= NN) rr = NN - 1;
            float4 v = *(const float4*)(x + (size_t)rr * 256 + k0 + kq * 4);
            ushort4 hi, lo;
            hi.x = f2bf(v.x); lo.x = f2bf(v.x - bf2f(hi.x));
            hi.y = f2bf(v.y); lo.y = f2bf(v.y - bf2f(hi.y));
            hi.z = f2bf(v.z); lo.z = f2bf(v.z - bf2f(hi.z));
            hi.w = f2bf(v.w); lo.w = f2bf(v.w - bf2f(hi.w));
            *(ushort4*)(Ah + r * AKP + kq * 4) = hi;
            *(ushort4*)(Al + r * AKP + kq * 4) = lo;
        }
        for (int id = tid; id < 272 * 4; id += 256) {
            int r = id >> 2, kq = id & 3;
            *(float4*)(Bhs + r * AKP + kq * 8) = *(const float4*)(Bh + (size_t)r * 256 + k0 + kq * 8);
            *(float4*)(Bls + r * AKP + kq * 8) = *(const float4*)(Bl + (size_t)r * 256 + k0 + kq * 8);
        }
        __syncthreads();
        short8_t ah[2], al[2];
        #pragma unroll
        for (int mt = 0; mt < 2; ++mt) {
            int mrow = wave * 32 + mt * 16 + l16;
            ah[mt] = *(const short8_t*)(Ah + mrow * AKP + quad * 8);
            al[mt] = *(const short8_t*)(Al + mrow * AKP + quad * 8);
        }
        #pragma unroll
        for (int nt = 0; nt < 17; ++nt) {
            int nrow = nt * 16 + l16;
            short8_t bh  = *(const short8_t*)(Bhs + nrow * AKP + quad * 8);
            short8_t blo = *(const short8_t*)(Bls + nrow * AKP + quad * 8);
            #pragma unroll
            for (int mt = 0; mt < 2; ++mt) {
                acc[mt][nt] = __builtin_amdgcn_mfma_f32_16x16x32_bf16(ah[mt], bh,  acc[mt][nt], 0, 0, 0);
                acc[mt][nt] = __builtin_amdgcn_mfma_f32_16x16x32_bf16(ah[mt], blo, acc[mt][nt], 0, 0, 0);
                acc[mt][nt] = __builtin_amdgcn_mfma_f32_16x16x32_bf16(al[mt], bh,  acc[mt][nt], 0, 0, 0);
            }
        }
    }
    #pragma unroll
    for (int mt = 0; mt < 2; ++mt) {
        int rbase = row0 + wave * 32 + mt * 16 + quad * 4;
        #pragma unroll
        for (int r = 0; r < 4; ++r) {
            int row = rbase + r;
            if (row >= NN) continue;
            #pragma unroll
            for (int nt = 0; nt < 16; ++nt)
                h1b[(size_t)row * 256 + nt * 16 + l16] = f2h(acc[mt][nt][r]);
            float v = acc[mt][16][r];
            if (l16 < 8) asrc1[row * 8 + l16] = v;
            else         adst1[row * 8 + (l16 - 8)] = v;
        }
    }
}

// ---------------- layer-1 aggregation: 3-pass per window, fp16 gather + fma_mix ----------------
#define WST 68
__global__ __launch_bounds__(256) void agg1_kernel(const unsigned short* __restrict__ h1b, const float* __restrict__ asrc,
                                                   const float* __restrict__ adst, const int* __restrict__ esrc,
                                                   const int* __restrict__ off,
                                                   const float* __restrict__ b1, unsigned short* __restrict__ hout) {
    __shared__ __align__(16) float wl[4][8 * WST];
    __shared__ __align__(16) int  snl[4][64];
    int tid = threadIdx.x;
    int wave = tid >> 6;
    int wid = blockIdx.x * 4 + wave;
    if (wid >= NN) return;
    int lane = tid & 63;
    int hp = lane & 7;        // phase head
    int jp = lane >> 3;       // phase edge slot
    int hc = lane >> 3;       // channel head
    int c0 = lane * 4;        // channels owned
    float adh_p = adst[wid * 8 + hp];
    int e0 = off[wid], e1 = off[wid + 1];
    float* wlw = wl[wave];
    int* snw = snl[wave];
    const char* hb = (const char*)h1b;
    unsigned lofs = (unsigned)c0 * 2;   // lane byte offset within a row

    float m = -INFINITY, s = 0.f;
    float ax = 0.f, ay = 0.f, az = 0.f, aw = 0.f;

    for (int base = e0; base < e1; base += 64) {
        int cnt = e1 - base; if (cnt > 64) cnt = 64;
        int snv = esrc[base + (lane < cnt ? lane : cnt - 1)];
        snw[lane] = snv;
        int nch = (cnt + 7) >> 3;
        // ---- pass A: logits into regs, window max ----
        float ee[8];
        float wmax = -INFINITY;
        #pragma unroll
        for (int cj = 0; cj < 8; ++cj) {
            if (cj >= nch) { ee[cj] = -INFINITY; continue; }
            int jedge = cj * 8 + jp;
            int sj = __shfl(snv, jedge);
            float a = asrc[sj * 8 + hp];
            float e = a + adh_p;
            e = (e >= 0.f) ? e : NEG * e;
            if (jedge >= cnt) e = -INFINITY;
            ee[cj] = e;
            wmax = fmaxf(wmax, e);
        }
        wmax = fmaxf(wmax, __shfl_xor(wmax, 8));
        wmax = fmaxf(wmax, __shfl_xor(wmax, 16));
        wmax = fmaxf(wmax, __shfl_xor(wmax, 32));   // per-head window max
        float mn = fmaxf(m, wmax);
        float t = __expf(m - mn);                   // uniform within head
        m = mn;
        s *= t;
        float tc = __shfl(t, hc);
        ax *= tc; ay *= tc; az *= tc; aw *= tc;
        // ---- pass B: weights -> LDS ----
        #pragma unroll
        for (int cj = 0; cj < 8; ++cj) {
            if (cj >= nch) break;
            float w = __expf(ee[cj] - mn);
            s += w;
            wlw[hp * WST + cj * 8 + jp] = w;
        }
        // ---- pass C: pure gather, fp16 decode folded into fma_mix ----
        const float* wrow = wlw + hc * WST;
        for (int j = 0; j < cnt; j += 4) {
            float4 w4 = *(const float4*)(wrow + j);
            int4 sn4 = *(const int4*)(snw + j);
            uint2 u0 = *(const uint2*)(hb + (((unsigned)sn4.x << 9) + lofs));
            uint2 u1 = *(const uint2*)(hb + (((unsigned)sn4.y << 9) + lofs));
            uint2 u2 = *(const uint2*)(hb + (((unsigned)sn4.z << 9) + lofs));
            uint2 u3 = *(const uint2*)(hb + (((unsigned)sn4.w << 9) + lofs));
            ax += w4.x * hlo2f(u0.x);
            ay += w4.x * hhi2f(u0.x);
            az += w4.x * hlo2f(u0.y);
            aw += w4.x * hhi2f(u0.y);
            ax += w4.y * hlo2f(u1.x);
            ay += w4.y * hhi2f(u1.x);
            az += w4.y * hlo2f(u1.y);
            aw += w4.y * hhi2f(u1.y);
            ax += w4.z * hlo2f(u2.x);
            ay += w4.z * hhi2f(u2.x);
            az += w4.z * hlo2f(u2.y);
            aw += w4.z * hhi2f(u2.y);
            ax += w4.w * hlo2f(u3.x);
            ay += w4.w * hhi2f(u3.x);
            az += w4.w * hlo2f(u3.y);
            aw += w4.w * hhi2f(u3.y);
        }
    }
    s += __shfl_xor(s, 8);
    s += __shfl_xor(s, 16);
    s += __shfl_xor(s, 32);
    float sh = __shfl(s, hc);
    float inv = 1.f / (sh + 1e-16f);
    float4 b = *(const float4*)(b1 + c0);
    float vx = ax * inv + b.x, vy = ay * inv + b.y, vz = az * inv + b.z, vw = aw * inv + b.w;
    ushort4 o;
    o.x = f2h((vx > 0.f) ? vx : expm1f(vx));
    o.y = f2h((vy > 0.f) ? vy : expm1f(vy));
    o.z = f2h((vz > 0.f) ? vz : expm1f(vz));
    o.w = f2h((vw > 0.f) ? vw : expm1f(vw));
    *(ushort4*)(hout + (size_t)wid * 256 + c0) = o;
}

// ---------------- GEMM2 (register-tiled, fp16 input) + fused alpha2, fp16 h2 out ----------------
#define G2_TM 128
#define G2_KC 32
__global__ __launch_bounds__(256) void gemm2_kernel(const unsigned short* __restrict__ h, const float* __restrict__ W2,
                                                    const float* __restrict__ at_s, const float* __restrict__ at_d,
                                                    unsigned short* __restrict__ h2b, float* __restrict__ as2,
                                                    float* __restrict__ ad2) {
    __shared__ __align__(16) float w2s[256 * 40];
    __shared__ __align__(16) float As[G2_KC][132];
    int tid = threadIdx.x;
    for (int i = tid; i < 256 * 40; i += 256) w2s[i] = W2[i];
    int g  = tid & 7;
    int rg = tid >> 3;
    int row0 = blockIdx.x * G2_TM;
    float acc[4][5] = {};
    float ats[5], atd[5];
    #pragma unroll
    for (int j = 0; j < 5; ++j) { ats[j] = at_s[g + 8 * j]; atd[j] = at_d[g + 8 * j]; }

    for (int k0 = 0; k0 < 256; k0 += G2_KC) {
        __syncthreads();
        #pragma unroll
        for (int i = 0; i < 2; ++i) {
            int id = i * 256 + tid;       // 0..511
            int r  = id >> 2;             // 0..127
            int kq = id & 3;              // 8-ushort group
            int rr = row0 + r; if (rr >= NN) rr = NN - 1;
            uint4 u = *(const uint4*)(h + (size_t)rr * 256 + k0 + kq * 8);
            As[kq * 8 + 0][r] = hlo2f(u.x);
            As[kq * 8 + 1][r] = hhi2f(u.x);
            As[kq * 8 + 2][r] = hlo2f(u.y);
            As[kq * 8 + 3][r] = hhi2f(u.y);
            As[kq * 8 + 4][r] = hlo2f(u.z);
            As[kq * 8 + 5][r] = hhi2f(u.z);
            As[kq * 8 + 6][r] = hlo2f(u.w);
            As[kq * 8 + 7][r] = hhi2f(u.w);
        }
        __syncthreads();
        #pragma unroll 4
        for (int k = 0; k < G2_KC; ++k) {
            float4 a = *(const float4*)(&As[k][rg * 4]);
            float w[5];
            #pragma unroll
            for (int j = 0; j < 5; ++j) w[j] = w2s[(k0 + k) * 40 + g + 8 * j];
            float av[4] = {a.x, a.y, a.z, a.w};
            #pragma unroll
            for (int r = 0; r < 4; ++r)
                #pragma unroll
                for (int j = 0; j < 5; ++j)
                    acc[r][j] += av[r] * w[j];
        }
    }

    #pragma unroll
    for (int r = 0; r < 4; ++r) {
        int row = row0 + rg * 4 + r;
        float ps = 0.f, pd = 0.f;
        #pragma unroll
        for (int j = 0; j < 5; ++j) {
            ps += acc[r][j] * ats[j];
            pd += acc[r][j] * atd[j];
        }
        ps += __shfl_xor(ps, 1); pd += __shfl_xor(pd, 1);
        ps += __shfl_xor(ps, 2); pd += __shfl_xor(pd, 2);
        ps += __shfl_xor(ps, 4); pd += __shfl_xor(pd, 4);
        if (row < NN) {
            #pragma unroll
            for (int j = 0; j < 5; ++j) h2b[(size_t)row * 40 + g + 8 * j] = f2h(acc[r][j]);
            if (g == 0) { as2[row] = ps; ad2[row] = pd; }
        }
    }
}

// ---------------- layer-2 aggregation: pass-separated, fp16 gather ----------------
__global__ __launch_bounds__(256) void agg2_kernel(const unsigned short* __restrict__ h2b, const float* __restrict__ asrc,
                                                   const float* __restrict__ adst, const int* __restrict__ esrc,
                                                   const int* __restrict__ off,
                                                   const float* __restrict__ b2, float* __restrict__ outF,
                                                   float* __restrict__ outL) {
    __shared__ __align__(16) float wl2[4][64];
    __shared__ __align__(16) int  snl2[4][64];
    int tid = threadIdx.x;
    int wave = tid >> 6;
    int wid = blockIdx.x * 4 + wave;
    if (wid >= NN) return;
    int lane = tid & 63;
    int c = lane;
    float adh = adst[wid];
    int e0 = off[wid], e1 = off[wid + 1];
    const char* hb = (const char*)h2b + ((unsigned)(c < NCLASS ? c : 0) << 1);
    float* wlw = wl2[wave];
    int* snw = snl2[wave];

    float m = -INFINITY, s = 0.f, acc = 0.f;

    for (int base = e0; base < e1; base += 64) {
        int cnt = e1 - base; if (cnt > 64) cnt = 64;
        int snv = esrc[base + (lane < cnt ? lane : cnt - 1)];
        snw[lane] = snv;
        float a = asrc[snv];
        float e = a + adh;
        e = (e >= 0.f) ? e : NEG * e;
        if (lane >= cnt) e = -INFINITY;
        float cm = e;
        cm = fmaxf(cm, __shfl_xor(cm, 1));
        cm = fmaxf(cm, __shfl_xor(cm, 2));
        cm = fmaxf(cm, __shfl_xor(cm, 4));
        cm = fmaxf(cm, __shfl_xor(cm, 8));
        cm = fmaxf(cm, __shfl_xor(cm, 16));
        cm = fmaxf(cm, __shfl_xor(cm, 32));
        float mn = fmaxf(m, cm);
        float t = __expf(m - mn);   // uniform across wave
        float w = __expf(e - mn);
        s = s * t + w;              // per-lane partial
        m = mn;
        wlw[lane] = w;
        acc *= t;
        for (int j = 0; j < cnt; j += 4) {
            float4 w4 = *(const float4*)(wlw + j);    // broadcast
            int4 sn4 = *(const int4*)(snw + j);
            unsigned short v0 = *(const unsigned short*)(hb + (unsigned)sn4.x * 80);
            unsigned short v1 = *(const unsigned short*)(hb + (unsigned)sn4.y * 80);
            unsigned short v2 = *(const unsigned short*)(hb + (unsigned)sn4.z * 80);
            unsigned short v3 = *(const unsigned short*)(hb + (unsigned)sn4.w * 80);
            acc += w4.x * h2f(v0);
            acc += w4.y * h2f(v1);
            acc += w4.z * h2f(v2);
            acc += w4.w * h2f(v3);
        }
    }
    s += __shfl_xor(s, 1);
    s += __shfl_xor(s, 2);
    s += __shfl_xor(s, 4);
    s += __shfl_xor(s, 8);
    s += __shfl_xor(s, 16);
    s += __shfl_xor(s, 32);
    float inv = 1.f / (s + 1e-16f);
    float fin = (c < NCLASS) ? (acc * inv + b2[c]) : -INFINITY;
    if (c < NCLASS) outF[(size_t)wid * 40 + c] = fin;
    float mx = fin;
    for (int o = 32; o; o >>= 1) mx = fmaxf(mx, __shfl_xor(mx, o));
    float ex = (c < NCLASS) ? __expf(fin - mx) : 0.f;
    float sm = ex;
    for (int o = 32; o; o >>= 1) sm += __shfl_xor(sm, o);
    if (c < NCLASS) outL[(size_t)wid * 40 + c] = fin - mx - __logf(sm);
}

extern "C" void kernel_launch(void* const* d_in, const int* in_sizes, int n_in,
                              void* d_out, int out_size, void* d_ws, size_t ws_size,
                              hipStream_t stream) {
    const float* x   = (const float*)d_in[0];
    const int*   ei  = (const int*)d_in[1];
    const float* W1  = (const float*)d_in[3];
    const float* as1 = (const float*)d_in[4];
    const float* ad1 = (const float*)d_in[5];
    const float* b1  = (const float*)d_in[6];
    const float* W2  = (const float*)d_in[7];
    const float* as2c = (const float*)d_in[8];
    const float* ad2c = (const float*)d_in[9];
    const float* b2  = (const float*)d_in[10];

    float* outF = (float*)d_out;
    float* outL = outF + (size_t)NN * NCLASS;

    char* w = (char*)d_ws;
    auto alloc = [&](size_t bytes) {
        void* p = (void*)w;
        w += (bytes + 255) & ~(size_t)255;
        return p;
    };
    unsigned short* h1b = (unsigned short*)alloc((size_t)NN * 256 * 2);
    unsigned short* hbuf = (unsigned short*)alloc((size_t)NN * 256 * 2);
    unsigned short* h2b = (unsigned short*)alloc((size_t)NN * 40 * 2);
    float* asrc1 = (float*)alloc((size_t)NN * 8 * 4);
    float* adst1 = (float*)alloc((size_t)NN * 8 * 4);
    float* asrc2 = (float*)alloc((size_t)NN * 4);
    float* adst2 = (float*)alloc((size_t)NN * 4);
    int* deg    = (int*)alloc((size_t)NN * 4);
    int* off    = (int*)alloc((size_t)(NN + 1) * 4);
    unsigned int* pack = (unsigned int*)alloc((size_t)ET * 4);
    int* esrc   = (int*)alloc((size_t)ET * 4);
    int* bsum   = (int*)alloc(64 * 4);
    unsigned short* W1th = (unsigned short*)alloc((size_t)272 * 256 * 2);
    unsigned short* W1tl = (unsigned short*)alloc((size_t)272 * 256 * 2);

    const int NB_SCAN = (NN + 1023) / 1024;  // 49

    hipMemsetAsync(deg, 0, (size_t)NN * 4, stream);

    hist_kernel<<<(ET + 255) / 256, 256, 0, stream>>>(ei, deg, pack);
    scan1_kernel<<<NB_SCAN, 256, 0, stream>>>(deg, off, bsum);
    scan2_kernel<<<1, 256, 0, stream>>>(bsum, NB_SCAN);
    scan3_kernel<<<NB_SCAN, 256, 0, stream>>>(off, bsum);
    scatter_kernel<<<(ET + 255) / 256, 256, 0, stream>>>(ei, off, pack, esrc);

    prep_kernel<<<272, 256, 0, stream>>>(W1, as1, ad1, W1th, W1tl);
    gemm1_kernel<<<(NN + 127) / 128, 256, 0, stream>>>(x, W1th, W1tl, h1b, asrc1, adst1);
    agg1_kernel<<<(NN + 3) / 4, 256, 0, stream>>>(h1b, asrc1, adst1, esrc, off, b1, hbuf);
    gemm2_kernel<<<(NN + G2_TM - 1) / G2_TM, 256, 0, stream>>>(hbuf, W2, as2c, ad2c, h2b, asrc2, adst2);
    agg2_kernel<<<(NN + 3) / 4, 256, 0, stream>>>(h2b, asrc2, adst2, esrc, off, b2, outF, outL);
}